// Round 6
// baseline (1456.341 us; speedup 1.0000x reference)
//
#include <hip/hip_runtime.h>
#include <hip/hip_bf16.h>

// ---------------------------------------------------------------------------
// THEGCNModel — R6:
//   * phase2_edge grid 768 -> 1280 + __launch_bounds__(256,5): R5 evidence
//     showed occupancy 33% was grid-limited (768/256 CU = 3 blk/CU); LDS 27KB
//     and VGPR 84 allow 5 blk/CU = 62%.
//   * edge sort output packed as int2(dst,src) + dts: 2 scattered lines/edge
//     instead of 3 in k_scatter; fewer staging loads in consumers.
// ---------------------------------------------------------------------------

typedef float  f32x4 __attribute__((ext_vector_type(4)));
typedef short  s16x8 __attribute__((ext_vector_type(8)));

__device__ __forceinline__ float tanh_factor(float u) {
  float e = __expf(2.0f * u);          // 2*tanh(u)-1 == 1 - 4/(exp(2u)+1)
  return 1.0f - 4.0f / (e + 1.0f);
}

__device__ __forceinline__ void atomic_add_f32(float* p, float v) {
  unsafeAtomicAdd(p, v);               // native global_atomic_add_f32
}

__device__ __forceinline__ unsigned short f2bf(float f) {
  __hip_bfloat16 b = __float2bfloat16(f);
  return *(unsigned short*)&b;
}

// ---------------------------------------------------------------------------
// Counting sort by dst: histogram -> 2-level exclusive scan -> scatter.
// ---------------------------------------------------------------------------
__global__ __launch_bounds__(256) void k_hist(
    const int* __restrict__ ei, int* __restrict__ cntI, int E)
{
  int e = blockIdx.x * 256 + threadIdx.x;
  if (e < E) atomicAdd(&cntI[ei[E + e]], 1);
}

__global__ __launch_bounds__(256) void k_scan_block(
    const int* __restrict__ cntI, int* __restrict__ cursor,
    int* __restrict__ bsum, int N)
{
  __shared__ int s[256];
  const int t = threadIdx.x;
  int i = blockIdx.x * 256 + t;
  int v = (i < N) ? cntI[i] : 0;
  s[t] = v;
  for (int off = 1; off < 256; off <<= 1) {
    __syncthreads();
    int x = (t >= off) ? s[t - off] : 0;
    __syncthreads();
    s[t] += x;
  }
  __syncthreads();
  if (i < N) cursor[i] = s[t] - v;          // local exclusive
  if (t == 255) bsum[blockIdx.x] = s[255];
}

__global__ __launch_bounds__(512) void k_scan_bsum(int* __restrict__ bsum, int nb)
{
  __shared__ int s[512];
  const int t = threadIdx.x;
  int v = (t < nb) ? bsum[t] : 0;
  s[t] = v;
  for (int off = 1; off < 512; off <<= 1) {
    __syncthreads();
    int x = (t >= off) ? s[t - off] : 0;
    __syncthreads();
    s[t] += x;
  }
  __syncthreads();
  if (t < nb) bsum[t] = s[t] - v;           // exclusive
}

__global__ __launch_bounds__(256) void k_scan_add(
    int* __restrict__ cursor, const int* __restrict__ bsum, int N)
{
  int i = blockIdx.x * 256 + threadIdx.x;
  if (i < N) cursor[i] += bsum[blockIdx.x];
}

__global__ __launch_bounds__(256) void k_scatter(
    const int* __restrict__ ei, const float* __restrict__ dts,
    int* __restrict__ cursor, int2* __restrict__ pairS,
    float* __restrict__ dtsS, int E)
{
  int e = blockIdx.x * 256 + threadIdx.x;
  if (e >= E) return;
  int d = ei[E + e];
  int pos = atomicAdd(&cursor[d], 1);
  pairS[pos] = make_int2(d, ei[e]);
  dtsS[pos] = dts[e];
}

// ---------------------------------------------------------------------------
// Phase 1 edge kernel: sorted edges, per-thread MLP, LDS segmented reduction
// of the 17 factors per dst-run, then atomics (one per run per col).
// ---------------------------------------------------------------------------
__global__ __launch_bounds__(256) void phase1_edge(
    const float* __restrict__ x, const int2* __restrict__ pairS,
    const float* __restrict__ dtsS,
    const float* __restrict__ freq, const float* __restrict__ phs,
    const float* __restrict__ W1, const float* __restrict__ b1,
    const float* __restrict__ W2, const float* __restrict__ b2,
    float* __restrict__ accum, int E)
{
  __shared__ float sF[256 * 17];
  __shared__ int   sDst[256];

  const int t = threadIdx.x;
  const int i = blockIdx.x * 256 + t;
  int dstn = 0;

  if (i < E) {
    int2 p = pairS[i];
    dstn = p.x;
    int srcn = p.y;

    float xi[17], xj[17];
#pragma unroll
    for (int c = 0; c < 17; c++) { xi[c] = x[dstn * 17 + c]; xj[c] = x[srcn * 17 + c]; }

    float dt = dtsS[i];
    float rel[32];
#pragma unroll
    for (int k = 0; k < 32; k++) rel[k] = __cosf(fmaf(dt, freq[k], phs[k]));

    float out[17];
#pragma unroll
    for (int c = 0; c < 17; c++) out[c] = b2[c];

#pragma unroll 3
    for (int j = 0; j < 33; j++) {
      float acc = b1[j];
#pragma unroll
      for (int k = 0; k < 17; k++) acc = fmaf(xi[k], W1[k * 33 + j], acc);
#pragma unroll
      for (int k = 0; k < 17; k++) acc = fmaf(xj[k], W1[(17 + k) * 33 + j], acc);
#pragma unroll
      for (int k = 0; k < 32; k++) acc = fmaf(rel[k], W1[(34 + k) * 33 + j], acc);
      acc = fmaxf(acc, 0.0f);
#pragma unroll
      for (int c = 0; c < 17; c++) out[c] = fmaf(acc, W2[j * 17 + c], out[c]);
    }

#pragma unroll
    for (int c = 0; c < 17; c++) sF[t * 17 + c] = tanh_factor(out[c]);
  } else {
#pragma unroll
    for (int c = 0; c < 17; c++) sF[t * 17 + c] = 0.0f;  // adds 0 to node 0
  }
  sDst[t] = dstn;
  __syncthreads();

  // segmented walk: worker (c, rowgroup of 16); 272 workers over 256 threads
  for (int w = t; w < 272; w += 256) {
    int c = w % 17;
    int r0 = (w / 17) * 16;
    float run = 0.0f;
    int cur = sDst[r0];
#pragma unroll
    for (int k = 0; k < 16; k++) {
      int r = r0 + k;
      int d = sDst[r];
      float v = sF[r * 17 + c];
      if (d != cur) {
        atomic_add_f32(&accum[(size_t)cur * 17 + c], run);
        run = 0.0f; cur = d;
      }
      run += v;
    }
    atomic_add_f32(&accum[(size_t)cur * 17 + c], run);
  }
}

// ---------------------------------------------------------------------------
// Phase 1 node kernel: h[n] = (x[n] * (1 + acc/max(cnt,1))) @ projW + projb.
// ---------------------------------------------------------------------------
__global__ __launch_bounds__(256) void phase1_node(
    const float* __restrict__ x, const float* __restrict__ acc1,
    const int* __restrict__ cntI, const float* __restrict__ Wp,
    const float* __restrict__ bp, float* __restrict__ h,
    unsigned short* __restrict__ hb, int N)
{
  __shared__ float s0[4][20];
  const int t = threadIdx.x;
  const int nb = blockIdx.x << 2;
  if (t < 68) {
    int nl = t / 17, c = t % 17;
    int n = nb + nl;
    float v = 0.0f;
    if (n < N) {
      float cnt = fmaxf((float)cntI[n], 1.0f);
      v = x[n * 17 + c] * (1.0f + acc1[n * 17 + c] / cnt);
    }
    s0[nl][c] = v;
  }
  __syncthreads();
  int nl = t >> 6, j = t & 63;
  int n = nb + nl;
  if (n < N) {
    float acc = bp[j];
#pragma unroll
    for (int c = 0; c < 17; c++) acc = fmaf(s0[nl][c], Wp[c * 64 + j], acc);
    h[n * 64 + j] = acc;
    hb[n * 64 + j] = f2bf(acc);
  }
}

// ---------------------------------------------------------------------------
// Weight prep: bf16-convert + transpose smp weights.
// ---------------------------------------------------------------------------
__global__ __launch_bounds__(256) void prep_w(
    const float* __restrict__ sW1, const float* __restrict__ sW2,
    unsigned short* __restrict__ W1t, unsigned short* __restrict__ W2t)
{
  int i = blockIdx.x * 256 + threadIdx.x;
  if (i < 2 * 64 * 128) {
    int l = i >> 13; int r = i & 8191; int n = r >> 7; int k = r & 127;
    W1t[i] = f2bf(sW1[((size_t)l * 128 + k) * 64 + n]);
  }
  if (i < 2 * 64 * 64) {
    int l = i >> 12; int r = i & 4095; int n = r >> 6; int k = r & 63;
    W2t[i] = f2bf(sW2[((size_t)l * 64 + k) * 64 + n]);
  }
}

// ---------------------------------------------------------------------------
// Phase 2 edge kernel (MFMA, weights in registers):
// 64-edge tiles (sorted by dst), 256 threads = 4 waves.
// B-fragments + biases in registers; LDS ~27KB; grid 1280 -> 5 blocks/CU.
// ---------------------------------------------------------------------------
__global__ __launch_bounds__(256, 5) void phase2_edge(
    const unsigned short* __restrict__ hb, const int2* __restrict__ pairS,
    const unsigned short* __restrict__ W1t, const float* __restrict__ b1,
    const unsigned short* __restrict__ W2t, const float* __restrict__ b2,
    float* __restrict__ accum, int E, int ntiles)
{
  __shared__ unsigned short sA[64][136];    // A-tile; aliased as f32[64][68] later
  __shared__ unsigned short sHid[64][72];
  __shared__ int   sDst[64];
  float* sRedF = (float*)&sA[0][0];         // 64 x 68 f32

  const int t = threadIdx.x;
  const int wv   = t >> 6;
  const int lane = t & 63;
  const int l16  = lane & 15;
  const int quad = lane >> 4;

  // loop-invariant weight fragments + biases -> registers
  s16x8 w1f[4][4], w2f[4][2];
  float bias1[4], bias2[4];
#pragma unroll
  for (int cb = 0; cb < 4; cb++) {
    const int n = cb * 16 + l16;
#pragma unroll
    for (int kb = 0; kb < 4; kb++)
      w1f[cb][kb] = *(const s16x8*)&W1t[n * 128 + kb * 32 + quad * 8];
#pragma unroll
    for (int kb = 0; kb < 2; kb++)
      w2f[cb][kb] = *(const s16x8*)&W2t[n * 64 + kb * 32 + quad * 8];
    bias1[cb] = b1[n];
    bias2[cb] = b2[n];
  }

  for (int tile = blockIdx.x; tile < ntiles; tile += gridDim.x) {
    const int eb = tile << 6;

    // stage A: row r = sorted edge eb+r; cols 0..63 = h[dst], 64..127 = h[src]
#pragma unroll
    for (int i = 0; i < 4; i++) {
      int g = t + i * 256; int r = g >> 4, c = g & 15;
      int er = eb + r; if (er >= E) er = E - 1;
      int2 p = pairS[er];
      int node = (c >= 8) ? p.y : p.x;
      if (c == 0) sDst[r] = p.x;
      *(uint4*)&sA[r][c * 8] = *(const uint4*)&hb[(size_t)node * 64 + (c & 7) * 8];
    }
    __syncthreads();                               // 1

    // pass 1: hidden = relu([h_i|h_j] @ W1 + b1)
    f32x4 acc[4];
#pragma unroll
    for (int cb = 0; cb < 4; cb++)
      acc[cb] = (f32x4){bias1[cb], bias1[cb], bias1[cb], bias1[cb]};
#pragma unroll
    for (int kb = 0; kb < 4; kb++) {
      s16x8 aF = *(const s16x8*)&sA[wv * 16 + l16][kb * 32 + quad * 8];
#pragma unroll
      for (int cb = 0; cb < 4; cb++)
        acc[cb] = __builtin_amdgcn_mfma_f32_16x16x32_bf16(aF, w1f[cb][kb], acc[cb], 0, 0, 0);
    }
#pragma unroll
    for (int cb = 0; cb < 4; cb++)
#pragma unroll
      for (int reg = 0; reg < 4; reg++)
        sHid[wv * 16 + quad * 4 + reg][cb * 16 + l16] = f2bf(fmaxf(acc[cb][reg], 0.0f));
    __syncthreads();                               // 2 (all sA reads done)

    // pass 2: u = hidden @ W2 + b2
#pragma unroll
    for (int cb = 0; cb < 4; cb++)
      acc[cb] = (f32x4){bias2[cb], bias2[cb], bias2[cb], bias2[cb]};
#pragma unroll
    for (int kb = 0; kb < 2; kb++) {
      s16x8 aF = *(const s16x8*)&sHid[wv * 16 + l16][kb * 32 + quad * 8];
#pragma unroll
      for (int cb = 0; cb < 4; cb++)
        acc[cb] = __builtin_amdgcn_mfma_f32_16x16x32_bf16(aF, w2f[cb][kb], acc[cb], 0, 0, 0);
    }

    // f = 2*tanh(u)-1 -> sRed (f32, aliases sA; safe after barrier 2)
#pragma unroll
    for (int cb = 0; cb < 4; cb++)
#pragma unroll
      for (int reg = 0; reg < 4; reg++) {
        int row = wv * 16 + quad * 4 + reg;
        float f = (eb + row < E) ? tanh_factor(acc[cb][reg]) : 0.0f;
        sRedF[row * 68 + cb * 16 + l16] = f;
      }
    __syncthreads();                               // 3

    // wave-uniform segmented walk: thread owns col j, rows r0..r0+15
    {
      int j = t & 63;
      int r0 = (t >> 6) * 16;
      float run = 0.0f;
      int cur = sDst[r0];
#pragma unroll
      for (int k = 0; k < 16; k++) {
        int r = r0 + k;
        int d = sDst[r];                 // wave-uniform
        float v = sRedF[r * 68 + j];
        if (d != cur) {                  // wave-uniform branch
          atomic_add_f32(&accum[(size_t)cur * 64 + j], run);
          run = 0.0f; cur = d;
        }
        run += v;
      }
      atomic_add_f32(&accum[(size_t)cur * 64 + j], run);
    }
    __syncthreads();                               // 4: sA/sDst reuse
  }
}

// ---------------------------------------------------------------------------
// Node update + BN statistics: h = h * (1 + acc/cnt); accumulate sum/sumsq.
// ---------------------------------------------------------------------------
__global__ __launch_bounds__(256) void node_update_bn(
    float* __restrict__ h, const float* __restrict__ accum,
    const int* __restrict__ cntI, float* __restrict__ bns,
    float* __restrict__ bnq, int N)
{
  const int t = threadIdx.x;
  float ls = 0.0f, lq = 0.0f;
  int total = N * 64;
  for (int idx = blockIdx.x * 256 + t; idx < total; idx += gridDim.x * 256) {
    int n = idx >> 6;
    float cnt = fmaxf((float)cntI[n], 1.0f);
    float v = h[idx] * (1.0f + accum[idx] / cnt);
    h[idx] = v;
    ls += v; lq += v * v;
  }
  __shared__ float ss[256], sq[256];
  ss[t] = ls; sq[t] = lq;
  __syncthreads();
  if (t < 64) {
    float s = ss[t] + ss[t + 64] + ss[t + 128] + ss[t + 192];
    float q = sq[t] + sq[t + 64] + sq[t + 128] + sq[t + 192];
    atomic_add_f32(&bns[t], s);
    atomic_add_f32(&bnq[t], q);
  }
}

// ---------------------------------------------------------------------------
// BN apply + relu (in place); optional bf16 mirror for next MFMA layer.
// ---------------------------------------------------------------------------
__global__ __launch_bounds__(256) void bn_apply_relu(
    float* __restrict__ d, const float* __restrict__ bns,
    const float* __restrict__ bnq, const float* __restrict__ gam,
    const float* __restrict__ bet, unsigned short* __restrict__ hbOut,
    int total, int cmask, float invRows)
{
  for (int idx = blockIdx.x * 256 + threadIdx.x; idx < total;
       idx += gridDim.x * 256) {
    int c = idx & cmask;
    float m = bns[c] * invRows;
    float var = bnq[c] * invRows - m * m;
    float sc = gam[c] * rsqrtf(var + 1e-5f);
    float v = fmaxf((d[idx] - m) * sc + bet[c], 0.0f);
    d[idx] = v;
    if (hbOut) hbOut[idx] = f2bf(v);
  }
}

// ---------------------------------------------------------------------------
// Classifier matmul (rows x K @ K x C) + bias, with BN stats.
// ---------------------------------------------------------------------------
__global__ __launch_bounds__(256) void clf_mm_bn(
    const float* __restrict__ in, const float* __restrict__ W,
    const float* __restrict__ b, float* __restrict__ out,
    float* __restrict__ bns, float* __restrict__ bnq,
    int rows, int K, int cshift)
{
  const int t = threadIdx.x;
  const int C = 1 << cshift;
  int total = rows << cshift;
  float ls = 0.0f, lq = 0.0f;
  for (int idx = blockIdx.x * 256 + t; idx < total; idx += gridDim.x * 256) {
    int n = idx >> cshift;
    int c = idx & (C - 1);
    float acc = b[c];
#pragma unroll 8
    for (int k = 0; k < K; k++) acc = fmaf(in[n * K + k], W[(k << cshift) + c], acc);
    out[idx] = acc;
    ls += acc; lq += acc * acc;
  }
  __shared__ float ss[256], sq[256];
  ss[t] = ls; sq[t] = lq;
  __syncthreads();
  if (t < C) {
    float s = 0.0f, q = 0.0f;
    for (int i = t; i < 256; i += C) { s += ss[i]; q += sq[i]; }
    atomic_add_f32(&bns[t], s);
    atomic_add_f32(&bnq[t], q);
  }
}

__global__ __launch_bounds__(256) void clf_final(
    const float* __restrict__ z2, const float* __restrict__ W3,
    const float* __restrict__ b3, float* __restrict__ out, int rows)
{
  int n = blockIdx.x * 256 + threadIdx.x;
  if (n >= rows) return;
  float acc = b3[0];
#pragma unroll
  for (int k = 0; k < 32; k++) acc = fmaf(z2[n * 32 + k], W3[k], acc);
  out[n] = acc;
}

// ---------------------------------------------------------------------------
extern "C" void kernel_launch(void* const* d_in, const int* in_sizes, int n_in,
                              void* d_out, int out_size, void* d_ws, size_t ws_size,
                              hipStream_t stream)
{
  const float* x    = (const float*)d_in[0];
  const int*   ei   = (const int*)  d_in[1];
  const float* dts  = (const float*)d_in[2];
  const float* freq = (const float*)d_in[4];
  const float* phs  = (const float*)d_in[5];
  const float* tW1  = (const float*)d_in[6];
  const float* tb1  = (const float*)d_in[7];
  const float* tW2  = (const float*)d_in[8];
  const float* tb2  = (const float*)d_in[9];
  const float* pW   = (const float*)d_in[10];
  const float* pb   = (const float*)d_in[11];
  const float* sW1  = (const float*)d_in[12];
  const float* sb1  = (const float*)d_in[13];
  const float* sW2  = (const float*)d_in[14];
  const float* sb2  = (const float*)d_in[15];
  const float* bng  = (const float*)d_in[16];
  const float* bnb  = (const float*)d_in[17];
  const float* cW1  = (const float*)d_in[18];
  const float* cb1  = (const float*)d_in[19];
  const float* cg1  = (const float*)d_in[20];
  const float* cbb1 = (const float*)d_in[21];
  const float* cW2  = (const float*)d_in[22];
  const float* cb2  = (const float*)d_in[23];
  const float* cg2  = (const float*)d_in[24];
  const float* cbb2 = (const float*)d_in[25];
  const float* cW3  = (const float*)d_in[26];
  const float* cb3  = (const float*)d_in[27];
  float* out = (float*)d_out;

  const int N = in_sizes[0] / 17;
  const int E = in_sizes[1] / 2;
  const int B = out_size;

  // workspace layout
  float* ws     = (float*)d_ws;
  float* h      = ws;                            // N*64
  float* acc2   = h    + (size_t)N * 64;         // N*64
  float* acc1   = acc2 + (size_t)N * 64;         // N*17 (z1/z2 alias)
  float* z1     = acc1;
  float* z2     = z1 + (size_t)B * 64;
  float* bns    = acc1 + (size_t)N * 17;         // 64
  float* bnq    = bns + 64;                      // 64
  unsigned short* hb  = (unsigned short*)(bnq + 64);   // N*64 bf16
  unsigned short* W1t = hb + (size_t)N * 64;           // 2*64*128
  unsigned short* W2t = W1t + 2 * 64 * 128;            // 2*64*64
  int*   cntI   = (int*)(W2t + 2 * 64 * 64);     // N
  int*   cursor = cntI + N;                      // N
  int*   bsum   = cursor + N;                    // 512
  int2*  pairS  = (int2*)(bsum + 512);           // E (dst,src)
  float* dtsS   = (float*)(pairS + (size_t)E);   // E
  size_t needed = (size_t)((char*)(dtsS + E) - (char*)d_ws);
  if (ws_size < needed) return;  // fail visibly (output stays poisoned)

  const int ntiles = (E + 63) / 64;
  const int NB = (N + 255) / 256;
  if (NB > 512) return;

  // ---- counting sort by dst (also yields counts) ----
  hipMemsetAsync(cntI, 0, (size_t)N * 4, stream);
  hipMemsetAsync(acc1, 0, (size_t)N * 17 * 4, stream);
  k_hist<<<(E + 255) / 256, 256, 0, stream>>>(ei, cntI, E);
  k_scan_block<<<NB, 256, 0, stream>>>(cntI, cursor, bsum, N);
  k_scan_bsum<<<1, 512, 0, stream>>>(bsum, NB);
  k_scan_add<<<NB, 256, 0, stream>>>(cursor, bsum, N);
  k_scatter<<<(E + 255) / 256, 256, 0, stream>>>(ei, dts, cursor, pairS, dtsS, E);
  prep_w<<<64, 256, 0, stream>>>(sW1, sW2, W1t, W2t);

  // ---- phase 1 ----
  phase1_edge<<<(E + 255) / 256, 256, 0, stream>>>(
      x, pairS, dtsS, freq, phs, tW1, tb1, tW2, tb2, acc1, E);
  phase1_node<<<(N + 3) / 4, 256, 0, stream>>>(x, acc1, cntI, pW, pb, h, hb, N);

  // ---- phase 2: L = 2 message-passing + BN layers ----
  for (int l = 0; l < 2; l++) {
    hipMemsetAsync(acc2, 0, (size_t)N * 64 * 4, stream);
    hipMemsetAsync(bns, 0, 128 * 4, stream);
    phase2_edge<<<1280, 256, 0, stream>>>(
        hb, pairS, W1t + (size_t)l * 64 * 128, sb1 + l * 64,
        W2t + (size_t)l * 64 * 64, sb2 + l * 64, acc2, E, ntiles);
    node_update_bn<<<1024, 256, 0, stream>>>(h, acc2, cntI, bns, bnq, N);
    bn_apply_relu<<<2048, 256, 0, stream>>>(
        h, bns, bnq, bng + l * 64, bnb + l * 64, hb, N * 64, 63, 1.0f / (float)N);
  }

  // ---- classifier on first B rows of h ----
  hipMemsetAsync(bns, 0, 128 * 4, stream);
  clf_mm_bn<<<2500, 256, 0, stream>>>(h, cW1, cb1, z1, bns, bnq, B, 64, 6);
  bn_apply_relu<<<1024, 256, 0, stream>>>(z1, bns, bnq, cg1, cbb1, nullptr,
                                          B * 64, 63, 1.0f / (float)B);
  hipMemsetAsync(bns, 0, 128 * 4, stream);
  clf_mm_bn<<<1250, 256, 0, stream>>>(z1, cW2, cb2, z2, bns, bnq, B, 64, 5);
  bn_apply_relu<<<512, 256, 0, stream>>>(z2, bns, bnq, cg2, cbb2, nullptr,
                                         B * 32, 31, 1.0f / (float)B);
  clf_final<<<(B + 255) / 256, 256, 0, stream>>>(z2, cW3, cb3, out, B);
}

// Round 7
// 1118.847 us; speedup vs baseline: 1.3016x; 1.3016x over previous
//
#include <hip/hip_runtime.h>
#include <hip/hip_bf16.h>

// ---------------------------------------------------------------------------
// THEGCNModel — R7: hybrid weight residency in phase2_edge.
//   R6 failed: bounds(256,5) cap ~102 regs < 96-reg weight set -> compiler
//   rematerialized weights from GLOBAL each tile (FETCH 103MB -> 1.22GB).
//   R7: W1 frags in registers (64 VGPR, 16 uses/tile); W2 in LDS staged once
//   (8 reads/tile). ~115 regs -> bounds(256,4); LDS 36.1KB -> 4 blocks/CU.
// ---------------------------------------------------------------------------

typedef float  f32x4 __attribute__((ext_vector_type(4)));
typedef short  s16x8 __attribute__((ext_vector_type(8)));

__device__ __forceinline__ float tanh_factor(float u) {
  float e = __expf(2.0f * u);          // 2*tanh(u)-1 == 1 - 4/(exp(2u)+1)
  return 1.0f - 4.0f / (e + 1.0f);
}

__device__ __forceinline__ void atomic_add_f32(float* p, float v) {
  unsafeAtomicAdd(p, v);               // native global_atomic_add_f32
}

__device__ __forceinline__ unsigned short f2bf(float f) {
  __hip_bfloat16 b = __float2bfloat16(f);
  return *(unsigned short*)&b;
}

// ---------------------------------------------------------------------------
// Counting sort by dst: histogram -> 2-level exclusive scan -> scatter.
// ---------------------------------------------------------------------------
__global__ __launch_bounds__(256) void k_hist(
    const int* __restrict__ ei, int* __restrict__ cntI, int E)
{
  int e = blockIdx.x * 256 + threadIdx.x;
  if (e < E) atomicAdd(&cntI[ei[E + e]], 1);
}

__global__ __launch_bounds__(256) void k_scan_block(
    const int* __restrict__ cntI, int* __restrict__ cursor,
    int* __restrict__ bsum, int N)
{
  __shared__ int s[256];
  const int t = threadIdx.x;
  int i = blockIdx.x * 256 + t;
  int v = (i < N) ? cntI[i] : 0;
  s[t] = v;
  for (int off = 1; off < 256; off <<= 1) {
    __syncthreads();
    int x = (t >= off) ? s[t - off] : 0;
    __syncthreads();
    s[t] += x;
  }
  __syncthreads();
  if (i < N) cursor[i] = s[t] - v;          // local exclusive
  if (t == 255) bsum[blockIdx.x] = s[255];
}

__global__ __launch_bounds__(512) void k_scan_bsum(int* __restrict__ bsum, int nb)
{
  __shared__ int s[512];
  const int t = threadIdx.x;
  int v = (t < nb) ? bsum[t] : 0;
  s[t] = v;
  for (int off = 1; off < 512; off <<= 1) {
    __syncthreads();
    int x = (t >= off) ? s[t - off] : 0;
    __syncthreads();
    s[t] += x;
  }
  __syncthreads();
  if (t < nb) bsum[t] = s[t] - v;           // exclusive
}

__global__ __launch_bounds__(256) void k_scan_add(
    int* __restrict__ cursor, const int* __restrict__ bsum, int N)
{
  int i = blockIdx.x * 256 + threadIdx.x;
  if (i < N) cursor[i] += bsum[blockIdx.x];
}

__global__ __launch_bounds__(256) void k_scatter(
    const int* __restrict__ ei, const float* __restrict__ dts,
    int* __restrict__ cursor, int2* __restrict__ pairS,
    float* __restrict__ dtsS, int E)
{
  int e = blockIdx.x * 256 + threadIdx.x;
  if (e >= E) return;
  int d = ei[E + e];
  int pos = atomicAdd(&cursor[d], 1);
  pairS[pos] = make_int2(d, ei[e]);
  dtsS[pos] = dts[e];
}

// ---------------------------------------------------------------------------
// Phase 1 edge kernel: sorted edges, per-thread MLP, LDS segmented reduction
// of the 17 factors per dst-run, then atomics (one per run per col).
// ---------------------------------------------------------------------------
__global__ __launch_bounds__(256) void phase1_edge(
    const float* __restrict__ x, const int2* __restrict__ pairS,
    const float* __restrict__ dtsS,
    const float* __restrict__ freq, const float* __restrict__ phs,
    const float* __restrict__ W1, const float* __restrict__ b1,
    const float* __restrict__ W2, const float* __restrict__ b2,
    float* __restrict__ accum, int E)
{
  __shared__ float sF[256 * 17];
  __shared__ int   sDst[256];

  const int t = threadIdx.x;
  const int i = blockIdx.x * 256 + t;
  int dstn = 0;

  if (i < E) {
    int2 p = pairS[i];
    dstn = p.x;
    int srcn = p.y;

    float xi[17], xj[17];
#pragma unroll
    for (int c = 0; c < 17; c++) { xi[c] = x[dstn * 17 + c]; xj[c] = x[srcn * 17 + c]; }

    float dt = dtsS[i];
    float rel[32];
#pragma unroll
    for (int k = 0; k < 32; k++) rel[k] = __cosf(fmaf(dt, freq[k], phs[k]));

    float out[17];
#pragma unroll
    for (int c = 0; c < 17; c++) out[c] = b2[c];

#pragma unroll 3
    for (int j = 0; j < 33; j++) {
      float acc = b1[j];
#pragma unroll
      for (int k = 0; k < 17; k++) acc = fmaf(xi[k], W1[k * 33 + j], acc);
#pragma unroll
      for (int k = 0; k < 17; k++) acc = fmaf(xj[k], W1[(17 + k) * 33 + j], acc);
#pragma unroll
      for (int k = 0; k < 32; k++) acc = fmaf(rel[k], W1[(34 + k) * 33 + j], acc);
      acc = fmaxf(acc, 0.0f);
#pragma unroll
      for (int c = 0; c < 17; c++) out[c] = fmaf(acc, W2[j * 17 + c], out[c]);
    }

#pragma unroll
    for (int c = 0; c < 17; c++) sF[t * 17 + c] = tanh_factor(out[c]);
  } else {
#pragma unroll
    for (int c = 0; c < 17; c++) sF[t * 17 + c] = 0.0f;  // adds 0 to node 0
  }
  sDst[t] = dstn;
  __syncthreads();

  // segmented walk: worker (c, rowgroup of 16); 272 workers over 256 threads
  for (int w = t; w < 272; w += 256) {
    int c = w % 17;
    int r0 = (w / 17) * 16;
    float run = 0.0f;
    int cur = sDst[r0];
#pragma unroll
    for (int k = 0; k < 16; k++) {
      int r = r0 + k;
      int d = sDst[r];
      float v = sF[r * 17 + c];
      if (d != cur) {
        atomic_add_f32(&accum[(size_t)cur * 17 + c], run);
        run = 0.0f; cur = d;
      }
      run += v;
    }
    atomic_add_f32(&accum[(size_t)cur * 17 + c], run);
  }
}

// ---------------------------------------------------------------------------
// Phase 1 node kernel: h[n] = (x[n] * (1 + acc/max(cnt,1))) @ projW + projb.
// ---------------------------------------------------------------------------
__global__ __launch_bounds__(256) void phase1_node(
    const float* __restrict__ x, const float* __restrict__ acc1,
    const int* __restrict__ cntI, const float* __restrict__ Wp,
    const float* __restrict__ bp, float* __restrict__ h,
    unsigned short* __restrict__ hb, int N)
{
  __shared__ float s0[4][20];
  const int t = threadIdx.x;
  const int nb = blockIdx.x << 2;
  if (t < 68) {
    int nl = t / 17, c = t % 17;
    int n = nb + nl;
    float v = 0.0f;
    if (n < N) {
      float cnt = fmaxf((float)cntI[n], 1.0f);
      v = x[n * 17 + c] * (1.0f + acc1[n * 17 + c] / cnt);
    }
    s0[nl][c] = v;
  }
  __syncthreads();
  int nl = t >> 6, j = t & 63;
  int n = nb + nl;
  if (n < N) {
    float acc = bp[j];
#pragma unroll
    for (int c = 0; c < 17; c++) acc = fmaf(s0[nl][c], Wp[c * 64 + j], acc);
    h[n * 64 + j] = acc;
    hb[n * 64 + j] = f2bf(acc);
  }
}

// ---------------------------------------------------------------------------
// Weight prep: bf16-convert + transpose smp weights.
// ---------------------------------------------------------------------------
__global__ __launch_bounds__(256) void prep_w(
    const float* __restrict__ sW1, const float* __restrict__ sW2,
    unsigned short* __restrict__ W1t, unsigned short* __restrict__ W2t)
{
  int i = blockIdx.x * 256 + threadIdx.x;
  if (i < 2 * 64 * 128) {
    int l = i >> 13; int r = i & 8191; int n = r >> 7; int k = r & 127;
    W1t[i] = f2bf(sW1[((size_t)l * 128 + k) * 64 + n]);
  }
  if (i < 2 * 64 * 64) {
    int l = i >> 12; int r = i & 4095; int n = r >> 6; int k = r & 63;
    W2t[i] = f2bf(sW2[((size_t)l * 64 + k) * 64 + n]);
  }
}

// ---------------------------------------------------------------------------
// Phase 2 edge kernel (MFMA, hybrid weight residency):
// 64-edge tiles (sorted by dst), 256 threads = 4 waves.
// W1 frags (64 VGPR) + biases in registers; W2 in LDS (staged once/block).
// LDS ~36.1KB, bounds(256,4), grid 1024 -> 4 blocks/CU.
// ---------------------------------------------------------------------------
__global__ __launch_bounds__(256, 4) void phase2_edge(
    const unsigned short* __restrict__ hb, const int2* __restrict__ pairS,
    const unsigned short* __restrict__ W1t, const float* __restrict__ b1,
    const unsigned short* __restrict__ W2t, const float* __restrict__ b2,
    float* __restrict__ accum, int E, int ntiles)
{
  __shared__ unsigned short sA[64][136];    // A-tile; aliased as f32[64][68] later
  __shared__ unsigned short sHid[64][72];
  __shared__ unsigned short sW2t[64][72];   // W2 [n][k], staged once per block
  __shared__ int   sDst[64];
  float* sRedF = (float*)&sA[0][0];         // 64 x 68 f32

  const int t = threadIdx.x;
  const int wv   = t >> 6;
  const int lane = t & 63;
  const int l16  = lane & 15;
  const int quad = lane >> 4;

  // W2 -> LDS once per block
#pragma unroll
  for (int i = 0; i < 2; i++) {
    int g = t + i * 256; int r = g >> 3, c = g & 7;
    *(uint4*)&sW2t[r][c * 8] = *(const uint4*)&W2t[r * 64 + c * 8];
  }

  // loop-invariant W1 fragments + biases -> registers (64 + 8 VGPR)
  s16x8 w1f[4][4];
  float bias1[4], bias2[4];
#pragma unroll
  for (int cb = 0; cb < 4; cb++) {
    const int n = cb * 16 + l16;
#pragma unroll
    for (int kb = 0; kb < 4; kb++)
      w1f[cb][kb] = *(const s16x8*)&W1t[n * 128 + kb * 32 + quad * 8];
    bias1[cb] = b1[n];
    bias2[cb] = b2[n];
  }
  __syncthreads();   // sW2t visible

  for (int tile = blockIdx.x; tile < ntiles; tile += gridDim.x) {
    const int eb = tile << 6;

    // stage A: row r = sorted edge eb+r; cols 0..63 = h[dst], 64..127 = h[src]
#pragma unroll
    for (int i = 0; i < 4; i++) {
      int g = t + i * 256; int r = g >> 4, c = g & 15;
      int er = eb + r; if (er >= E) er = E - 1;
      int2 p = pairS[er];
      int node = (c >= 8) ? p.y : p.x;
      if (c == 0) sDst[r] = p.x;
      *(uint4*)&sA[r][c * 8] = *(const uint4*)&hb[(size_t)node * 64 + (c & 7) * 8];
    }
    __syncthreads();                               // 1

    // pass 1: hidden = relu([h_i|h_j] @ W1 + b1)   (W1 from registers)
    f32x4 acc[4];
#pragma unroll
    for (int cb = 0; cb < 4; cb++)
      acc[cb] = (f32x4){bias1[cb], bias1[cb], bias1[cb], bias1[cb]};
#pragma unroll
    for (int kb = 0; kb < 4; kb++) {
      s16x8 aF = *(const s16x8*)&sA[wv * 16 + l16][kb * 32 + quad * 8];
#pragma unroll
      for (int cb = 0; cb < 4; cb++)
        acc[cb] = __builtin_amdgcn_mfma_f32_16x16x32_bf16(aF, w1f[cb][kb], acc[cb], 0, 0, 0);
    }
#pragma unroll
    for (int cb = 0; cb < 4; cb++)
#pragma unroll
      for (int reg = 0; reg < 4; reg++)
        sHid[wv * 16 + quad * 4 + reg][cb * 16 + l16] = f2bf(fmaxf(acc[cb][reg], 0.0f));
    __syncthreads();                               // 2 (all sA reads done)

    // pass 2: u = hidden @ W2 + b2                 (W2 from LDS)
#pragma unroll
    for (int cb = 0; cb < 4; cb++)
      acc[cb] = (f32x4){bias2[cb], bias2[cb], bias2[cb], bias2[cb]};
#pragma unroll
    for (int kb = 0; kb < 2; kb++) {
      s16x8 aF = *(const s16x8*)&sHid[wv * 16 + l16][kb * 32 + quad * 8];
#pragma unroll
      for (int cb = 0; cb < 4; cb++) {
        s16x8 bF = *(const s16x8*)&sW2t[cb * 16 + l16][kb * 32 + quad * 8];
        acc[cb] = __builtin_amdgcn_mfma_f32_16x16x32_bf16(aF, bF, acc[cb], 0, 0, 0);
      }
    }

    // f = 2*tanh(u)-1 -> sRed (f32, aliases sA; safe after barrier 2)
#pragma unroll
    for (int cb = 0; cb < 4; cb++)
#pragma unroll
      for (int reg = 0; reg < 4; reg++) {
        int row = wv * 16 + quad * 4 + reg;
        float f = (eb + row < E) ? tanh_factor(acc[cb][reg]) : 0.0f;
        sRedF[row * 68 + cb * 16 + l16] = f;
      }
    __syncthreads();                               // 3

    // wave-uniform segmented walk: thread owns col j, rows r0..r0+15
    {
      int j = t & 63;
      int r0 = (t >> 6) * 16;
      float run = 0.0f;
      int cur = sDst[r0];
#pragma unroll
      for (int k = 0; k < 16; k++) {
        int r = r0 + k;
        int d = sDst[r];                 // wave-uniform
        float v = sRedF[r * 68 + j];
        if (d != cur) {                  // wave-uniform branch
          atomic_add_f32(&accum[(size_t)cur * 64 + j], run);
          run = 0.0f; cur = d;
        }
        run += v;
      }
      atomic_add_f32(&accum[(size_t)cur * 64 + j], run);
    }
    __syncthreads();                               // 4: sA/sDst reuse
  }
}

// ---------------------------------------------------------------------------
// Node update + BN statistics: h = h * (1 + acc/cnt); accumulate sum/sumsq.
// ---------------------------------------------------------------------------
__global__ __launch_bounds__(256) void node_update_bn(
    float* __restrict__ h, const float* __restrict__ accum,
    const int* __restrict__ cntI, float* __restrict__ bns,
    float* __restrict__ bnq, int N)
{
  const int t = threadIdx.x;
  float ls = 0.0f, lq = 0.0f;
  int total = N * 64;
  for (int idx = blockIdx.x * 256 + t; idx < total; idx += gridDim.x * 256) {
    int n = idx >> 6;
    float cnt = fmaxf((float)cntI[n], 1.0f);
    float v = h[idx] * (1.0f + accum[idx] / cnt);
    h[idx] = v;
    ls += v; lq += v * v;
  }
  __shared__ float ss[256], sq[256];
  ss[t] = ls; sq[t] = lq;
  __syncthreads();
  if (t < 64) {
    float s = ss[t] + ss[t + 64] + ss[t + 128] + ss[t + 192];
    float q = sq[t] + sq[t + 64] + sq[t + 128] + sq[t + 192];
    atomic_add_f32(&bns[t], s);
    atomic_add_f32(&bnq[t], q);
  }
}

// ---------------------------------------------------------------------------
// BN apply + relu (in place); optional bf16 mirror for next MFMA layer.
// ---------------------------------------------------------------------------
__global__ __launch_bounds__(256) void bn_apply_relu(
    float* __restrict__ d, const float* __restrict__ bns,
    const float* __restrict__ bnq, const float* __restrict__ gam,
    const float* __restrict__ bet, unsigned short* __restrict__ hbOut,
    int total, int cmask, float invRows)
{
  for (int idx = blockIdx.x * 256 + threadIdx.x; idx < total;
       idx += gridDim.x * 256) {
    int c = idx & cmask;
    float m = bns[c] * invRows;
    float var = bnq[c] * invRows - m * m;
    float sc = gam[c] * rsqrtf(var + 1e-5f);
    float v = fmaxf((d[idx] - m) * sc + bet[c], 0.0f);
    d[idx] = v;
    if (hbOut) hbOut[idx] = f2bf(v);
  }
}

// ---------------------------------------------------------------------------
// Classifier matmul (rows x K @ K x C) + bias, with BN stats.
// ---------------------------------------------------------------------------
__global__ __launch_bounds__(256) void clf_mm_bn(
    const float* __restrict__ in, const float* __restrict__ W,
    const float* __restrict__ b, float* __restrict__ out,
    float* __restrict__ bns, float* __restrict__ bnq,
    int rows, int K, int cshift)
{
  const int t = threadIdx.x;
  const int C = 1 << cshift;
  int total = rows << cshift;
  float ls = 0.0f, lq = 0.0f;
  for (int idx = blockIdx.x * 256 + t; idx < total; idx += gridDim.x * 256) {
    int n = idx >> cshift;
    int c = idx & (C - 1);
    float acc = b[c];
#pragma unroll 8
    for (int k = 0; k < K; k++) acc = fmaf(in[n * K + k], W[(k << cshift) + c], acc);
    out[idx] = acc;
    ls += acc; lq += acc * acc;
  }
  __shared__ float ss[256], sq[256];
  ss[t] = ls; sq[t] = lq;
  __syncthreads();
  if (t < C) {
    float s = 0.0f, q = 0.0f;
    for (int i = t; i < 256; i += C) { s += ss[i]; q += sq[i]; }
    atomic_add_f32(&bns[t], s);
    atomic_add_f32(&bnq[t], q);
  }
}

__global__ __launch_bounds__(256) void clf_final(
    const float* __restrict__ z2, const float* __restrict__ W3,
    const float* __restrict__ b3, float* __restrict__ out, int rows)
{
  int n = blockIdx.x * 256 + threadIdx.x;
  if (n >= rows) return;
  float acc = b3[0];
#pragma unroll
  for (int k = 0; k < 32; k++) acc = fmaf(z2[n * 32 + k], W3[k], acc);
  out[n] = acc;
}

// ---------------------------------------------------------------------------
extern "C" void kernel_launch(void* const* d_in, const int* in_sizes, int n_in,
                              void* d_out, int out_size, void* d_ws, size_t ws_size,
                              hipStream_t stream)
{
  const float* x    = (const float*)d_in[0];
  const int*   ei   = (const int*)  d_in[1];
  const float* dts  = (const float*)d_in[2];
  const float* freq = (const float*)d_in[4];
  const float* phs  = (const float*)d_in[5];
  const float* tW1  = (const float*)d_in[6];
  const float* tb1  = (const float*)d_in[7];
  const float* tW2  = (const float*)d_in[8];
  const float* tb2  = (const float*)d_in[9];
  const float* pW   = (const float*)d_in[10];
  const float* pb   = (const float*)d_in[11];
  const float* sW1  = (const float*)d_in[12];
  const float* sb1  = (const float*)d_in[13];
  const float* sW2  = (const float*)d_in[14];
  const float* sb2  = (const float*)d_in[15];
  const float* bng  = (const float*)d_in[16];
  const float* bnb  = (const float*)d_in[17];
  const float* cW1  = (const float*)d_in[18];
  const float* cb1  = (const float*)d_in[19];
  const float* cg1  = (const float*)d_in[20];
  const float* cbb1 = (const float*)d_in[21];
  const float* cW2  = (const float*)d_in[22];
  const float* cb2  = (const float*)d_in[23];
  const float* cg2  = (const float*)d_in[24];
  const float* cbb2 = (const float*)d_in[25];
  const float* cW3  = (const float*)d_in[26];
  const float* cb3  = (const float*)d_in[27];
  float* out = (float*)d_out;

  const int N = in_sizes[0] / 17;
  const int E = in_sizes[1] / 2;
  const int B = out_size;

  // workspace layout
  float* ws     = (float*)d_ws;
  float* h      = ws;                            // N*64
  float* acc2   = h    + (size_t)N * 64;         // N*64
  float* acc1   = acc2 + (size_t)N * 64;         // N*17 (z1/z2 alias)
  float* z1     = acc1;
  float* z2     = z1 + (size_t)B * 64;
  float* bns    = acc1 + (size_t)N * 17;         // 64
  float* bnq    = bns + 64;                      // 64
  unsigned short* hb  = (unsigned short*)(bnq + 64);   // N*64 bf16
  unsigned short* W1t = hb + (size_t)N * 64;           // 2*64*128
  unsigned short* W2t = W1t + 2 * 64 * 128;            // 2*64*64
  int*   cntI   = (int*)(W2t + 2 * 64 * 64);     // N
  int*   cursor = cntI + N;                      // N
  int*   bsum   = cursor + N;                    // 512
  int2*  pairS  = (int2*)(bsum + 512);           // E (dst,src)
  float* dtsS   = (float*)(pairS + (size_t)E);   // E
  size_t needed = (size_t)((char*)(dtsS + E) - (char*)d_ws);
  if (ws_size < needed) return;  // fail visibly (output stays poisoned)

  const int ntiles = (E + 63) / 64;
  const int NB = (N + 255) / 256;
  if (NB > 512) return;

  // ---- counting sort by dst (also yields counts) ----
  hipMemsetAsync(cntI, 0, (size_t)N * 4, stream);
  hipMemsetAsync(acc1, 0, (size_t)N * 17 * 4, stream);
  k_hist<<<(E + 255) / 256, 256, 0, stream>>>(ei, cntI, E);
  k_scan_block<<<NB, 256, 0, stream>>>(cntI, cursor, bsum, N);
  k_scan_bsum<<<1, 512, 0, stream>>>(bsum, NB);
  k_scan_add<<<NB, 256, 0, stream>>>(cursor, bsum, N);
  k_scatter<<<(E + 255) / 256, 256, 0, stream>>>(ei, dts, cursor, pairS, dtsS, E);
  prep_w<<<64, 256, 0, stream>>>(sW1, sW2, W1t, W2t);

  // ---- phase 1 ----
  phase1_edge<<<(E + 255) / 256, 256, 0, stream>>>(
      x, pairS, dtsS, freq, phs, tW1, tb1, tW2, tb2, acc1, E);
  phase1_node<<<(N + 3) / 4, 256, 0, stream>>>(x, acc1, cntI, pW, pb, h, hb, N);

  // ---- phase 2: L = 2 message-passing + BN layers ----
  for (int l = 0; l < 2; l++) {
    hipMemsetAsync(acc2, 0, (size_t)N * 64 * 4, stream);
    hipMemsetAsync(bns, 0, 128 * 4, stream);
    phase2_edge<<<1024, 256, 0, stream>>>(
        hb, pairS, W1t + (size_t)l * 64 * 128, sb1 + l * 64,
        W2t + (size_t)l * 64 * 64, sb2 + l * 64, acc2, E, ntiles);
    node_update_bn<<<1024, 256, 0, stream>>>(h, acc2, cntI, bns, bnq, N);
    bn_apply_relu<<<2048, 256, 0, stream>>>(
        h, bns, bnq, bng + l * 64, bnb + l * 64, hb, N * 64, 63, 1.0f / (float)N);
  }

  // ---- classifier on first B rows of h ----
  hipMemsetAsync(bns, 0, 128 * 4, stream);
  clf_mm_bn<<<2500, 256, 0, stream>>>(h, cW1, cb1, z1, bns, bnq, B, 64, 6);
  bn_apply_relu<<<1024, 256, 0, stream>>>(z1, bns, bnq, cg1, cbb1, nullptr,
                                          B * 64, 63, 1.0f / (float)B);
  hipMemsetAsync(bns, 0, 128 * 4, stream);
  clf_mm_bn<<<1250, 256, 0, stream>>>(z1, cW2, cb2, z2, bns, bnq, B, 64, 5);
  bn_apply_relu<<<512, 256, 0, stream>>>(z2, bns, bnq, cg2, cbb2, nullptr,
                                         B * 32, 31, 1.0f / (float)B);
  clf_final<<<(B + 255) / 256, 256, 0, stream>>>(z2, cW3, cb3, out, B);
}

// Round 8
// 1023.749 us; speedup vs baseline: 1.4226x; 1.0929x over previous
//
#include <hip/hip_runtime.h>
#include <hip/hip_bf16.h>

// ---------------------------------------------------------------------------
// THEGCNModel — R8:
//   * phase2_edge reverted to R5-exact config (all weight frags in registers,
//     __launch_bounds__(256,3), grid 768). R6/R7 evidence: any tighter reg cap
//     makes the compiler rematerialize weight loads per tile (FETCH 3-12x).
//   * phase1_edge rewritten as bf16 MFMA (was 2178 serial f32 FMA/edge):
//     A-tile = [xi|pad|xj|pad|rel|pad] 64x96 bf16, W1/W2 frags in registers.
// ---------------------------------------------------------------------------

typedef float  f32x4 __attribute__((ext_vector_type(4)));
typedef short  s16x8 __attribute__((ext_vector_type(8)));

__device__ __forceinline__ float tanh_factor(float u) {
  float e = __expf(2.0f * u);          // 2*tanh(u)-1 == 1 - 4/(exp(2u)+1)
  return 1.0f - 4.0f / (e + 1.0f);
}

__device__ __forceinline__ void atomic_add_f32(float* p, float v) {
  unsafeAtomicAdd(p, v);               // native global_atomic_add_f32
}

__device__ __forceinline__ unsigned short f2bf(float f) {
  __hip_bfloat16 b = __float2bfloat16(f);
  return *(unsigned short*)&b;
}

// ---------------------------------------------------------------------------
// Counting sort by dst: histogram -> 2-level exclusive scan -> scatter.
// ---------------------------------------------------------------------------
__global__ __launch_bounds__(256) void k_hist(
    const int* __restrict__ ei, int* __restrict__ cntI, int E)
{
  int e = blockIdx.x * 256 + threadIdx.x;
  if (e < E) atomicAdd(&cntI[ei[E + e]], 1);
}

__global__ __launch_bounds__(256) void k_scan_block(
    const int* __restrict__ cntI, int* __restrict__ cursor,
    int* __restrict__ bsum, int N)
{
  __shared__ int s[256];
  const int t = threadIdx.x;
  int i = blockIdx.x * 256 + t;
  int v = (i < N) ? cntI[i] : 0;
  s[t] = v;
  for (int off = 1; off < 256; off <<= 1) {
    __syncthreads();
    int x = (t >= off) ? s[t - off] : 0;
    __syncthreads();
    s[t] += x;
  }
  __syncthreads();
  if (i < N) cursor[i] = s[t] - v;          // local exclusive
  if (t == 255) bsum[blockIdx.x] = s[255];
}

__global__ __launch_bounds__(512) void k_scan_bsum(int* __restrict__ bsum, int nb)
{
  __shared__ int s[512];
  const int t = threadIdx.x;
  int v = (t < nb) ? bsum[t] : 0;
  s[t] = v;
  for (int off = 1; off < 512; off <<= 1) {
    __syncthreads();
    int x = (t >= off) ? s[t - off] : 0;
    __syncthreads();
    s[t] += x;
  }
  __syncthreads();
  if (t < nb) bsum[t] = s[t] - v;           // exclusive
}

__global__ __launch_bounds__(256) void k_scan_add(
    int* __restrict__ cursor, const int* __restrict__ bsum, int N)
{
  int i = blockIdx.x * 256 + threadIdx.x;
  if (i < N) cursor[i] += bsum[blockIdx.x];
}

__global__ __launch_bounds__(256) void k_scatter(
    const int* __restrict__ ei, const float* __restrict__ dts,
    int* __restrict__ cursor, int2* __restrict__ pairS,
    float* __restrict__ dtsS, int E)
{
  int e = blockIdx.x * 256 + threadIdx.x;
  if (e >= E) return;
  int d = ei[E + e];
  int pos = atomicAdd(&cursor[d], 1);
  pairS[pos] = make_int2(d, ei[e]);
  dtsS[pos] = dts[e];
}

// ---------------------------------------------------------------------------
// prep1: xb = bf16(x) padded to 24 cols; W1t1[n:48][k:96], W2t1[n:32][k:64]
// transposed+padded phase-1 MLP weights. k-map for W1t1:
//   k<17 -> xi row k; 24<=k<41 -> xj row k-24+17; 48<=k<80 -> rel row k-48+34.
// ---------------------------------------------------------------------------
__global__ __launch_bounds__(256) void prep1(
    const float* __restrict__ x, const float* __restrict__ tW1,
    const float* __restrict__ tW2, unsigned short* __restrict__ xb,
    unsigned short* __restrict__ W1t1, unsigned short* __restrict__ W2t1, int N)
{
  int i = blockIdx.x * 256 + threadIdx.x;
  int totalX = N * 24;
  for (int idx = i; idx < totalX; idx += gridDim.x * 256) {
    int n = idx / 24, c = idx - n * 24;
    xb[idx] = (c < 17) ? f2bf(x[n * 17 + c]) : (unsigned short)0;
  }
  if (i < 48 * 96) {
    int n = i / 96, k = i - n * 96;
    int src = (k < 17) ? k : (k >= 24 && k < 41) ? (k - 24 + 17)
            : (k >= 48 && k < 80) ? (k - 48 + 34) : -1;
    W1t1[i] = (n < 33 && src >= 0) ? f2bf(tW1[src * 33 + n]) : (unsigned short)0;
  }
  if (i < 32 * 64) {
    int n = i / 64, k = i - n * 64;
    W2t1[i] = (n < 17 && k < 33) ? f2bf(tW2[k * 17 + n]) : (unsigned short)0;
  }
}

// ---------------------------------------------------------------------------
// Phase 1 edge kernel (MFMA): 64-edge tiles (sorted by dst), 256 thr = 4 waves.
// pass1: hid(64x48) = relu(A(64x96) @ W1t1); pass2: u(64x32) = hid @ W2t1.
// Weight frags (9+4 s16x8 = 52 VGPR) in registers. Epilogue = segmented walk.
// ---------------------------------------------------------------------------
__global__ __launch_bounds__(256, 3) void phase1_edge_mfma(
    const unsigned short* __restrict__ xb, const int2* __restrict__ pairS,
    const float* __restrict__ dtsS, const float* __restrict__ freq,
    const float* __restrict__ phs,
    const unsigned short* __restrict__ W1t1, const float* __restrict__ b1,
    const unsigned short* __restrict__ W2t1, const float* __restrict__ b2,
    float* __restrict__ accum, int E, int ntiles)
{
  __shared__ unsigned short sA[64][104];   // cols: 0..17 xi(+pad), 24..41 xj(+pad), 48..79 rel, rest pad
  __shared__ unsigned short sHid[64][72];  // cols 0..47 hid, 48..63 zero
  __shared__ float sRed[64][20];           // 17 factor cols
  __shared__ int   sDst[64];

  const int t = threadIdx.x;
  const int wv = t >> 6, lane = t & 63, l16 = lane & 15, quad = lane >> 4;

  // weight fragments + biases -> registers
  s16x8 w1f[3][3], w2f[2][2];
  float bias1[3], bias2[2];
#pragma unroll
  for (int cb = 0; cb < 3; cb++) {
    int n = cb * 16 + l16;
#pragma unroll
    for (int kb = 0; kb < 3; kb++)
      w1f[cb][kb] = *(const s16x8*)&W1t1[n * 96 + kb * 32 + quad * 8];
    bias1[cb] = (n < 33) ? b1[n] : 0.0f;
  }
#pragma unroll
  for (int cb = 0; cb < 2; cb++) {
    int n = cb * 16 + l16;
#pragma unroll
    for (int kb = 0; kb < 2; kb++)
      w2f[cb][kb] = *(const s16x8*)&W2t1[n * 64 + kb * 32 + quad * 8];
    bias2[cb] = (n < 17) ? b2[n] : 0.0f;
  }

  // zero never-written pad columns once (avoid NaN garbage x 0-weight rows)
  for (int i = t; i < 64 * 28; i += 256) {
    int r = i / 28, c = i - r * 28;
    int col = (c < 6) ? 18 + c : (c < 12) ? 42 + (c - 6) : 80 + (c - 12);
    sA[r][col] = 0;
  }
  for (int i = t; i < 64 * 16; i += 256) {
    int r = i >> 4, c = 48 + (i & 15);
    sHid[r][c] = 0;
  }

  for (int tile = blockIdx.x; tile < ntiles; tile += gridDim.x) {
    const int eb = tile << 6;

    // staging: 4 threads per edge (q0: xi, q1: xj, q2/q3: rel halves)
    {
      int e_l = t >> 2, q = t & 3;
      int er = eb + e_l; if (er >= E) er = E - 1;
      if (q < 2) {
        int2 p = pairS[er];
        int node = q ? p.y : p.x;
        if (!q) sDst[e_l] = p.x;
        const unsigned short* src = &xb[(size_t)node * 24];
        int base = q ? 24 : 0;
        *(uint4*)&sA[e_l][base]     = *(const uint4*)&src[0];
        *(uint4*)&sA[e_l][base + 8] = *(const uint4*)&src[8];
        *(unsigned int*)&sA[e_l][base + 16] = *(const unsigned int*)&src[16];
      } else {
        float dt = dtsS[er];
        int k0 = (q == 2) ? 0 : 16;
        unsigned short tmp[16] __attribute__((aligned(16)));
#pragma unroll
        for (int j = 0; j < 16; j++)
          tmp[j] = f2bf(__cosf(fmaf(dt, freq[k0 + j], phs[k0 + j])));
        *(uint4*)&sA[e_l][48 + k0]     = *(const uint4*)&tmp[0];
        *(uint4*)&sA[e_l][48 + k0 + 8] = *(const uint4*)&tmp[8];
      }
    }
    __syncthreads();                               // 1

    // pass1: hid = relu(A @ W1 + b1)
    f32x4 a1[3];
#pragma unroll
    for (int cb = 0; cb < 3; cb++)
      a1[cb] = (f32x4){bias1[cb], bias1[cb], bias1[cb], bias1[cb]};
#pragma unroll
    for (int kb = 0; kb < 3; kb++) {
      s16x8 aF = *(const s16x8*)&sA[wv * 16 + l16][kb * 32 + quad * 8];
#pragma unroll
      for (int cb = 0; cb < 3; cb++)
        a1[cb] = __builtin_amdgcn_mfma_f32_16x16x32_bf16(aF, w1f[cb][kb], a1[cb], 0, 0, 0);
    }
#pragma unroll
    for (int cb = 0; cb < 3; cb++)
#pragma unroll
      for (int reg = 0; reg < 4; reg++)
        sHid[wv * 16 + quad * 4 + reg][cb * 16 + l16] = f2bf(fmaxf(a1[cb][reg], 0.0f));
    __syncthreads();                               // 2

    // pass2: u = hid @ W2 + b2
    f32x4 a2[2];
#pragma unroll
    for (int cb = 0; cb < 2; cb++)
      a2[cb] = (f32x4){bias2[cb], bias2[cb], bias2[cb], bias2[cb]};
#pragma unroll
    for (int kb = 0; kb < 2; kb++) {
      s16x8 aF = *(const s16x8*)&sHid[wv * 16 + l16][kb * 32 + quad * 8];
#pragma unroll
      for (int cb = 0; cb < 2; cb++)
        a2[cb] = __builtin_amdgcn_mfma_f32_16x16x32_bf16(aF, w2f[cb][kb], a2[cb], 0, 0, 0);
    }

    // f = 2*tanh(u)-1 -> sRed (cols 0..16)
#pragma unroll
    for (int reg = 0; reg < 4; reg++) {
      int row = wv * 16 + quad * 4 + reg;
      bool ok = (eb + row < E);
      sRed[row][l16] = ok ? tanh_factor(a2[0][reg]) : 0.0f;
      if (l16 == 0) sRed[row][16] = ok ? tanh_factor(a2[1][reg]) : 0.0f;
    }
    __syncthreads();                               // 3

    // segmented walk: worker (col, rowgroup of 16); 68 workers
    if (t < 68) {
      int col = t % 17;
      int r0 = (t / 17) * 16;
      float run = 0.0f;
      int cur = sDst[r0];
#pragma unroll
      for (int k = 0; k < 16; k++) {
        int r = r0 + k;
        int d = sDst[r];
        float v = sRed[r][col];
        if (d != cur) {
          atomic_add_f32(&accum[(size_t)cur * 17 + col], run);
          run = 0.0f; cur = d;
        }
        run += v;
      }
      atomic_add_f32(&accum[(size_t)cur * 17 + col], run);
    }
    __syncthreads();                               // 4: sA/sDst/sRed reuse
  }
}

// ---------------------------------------------------------------------------
// Phase 1 node kernel: h[n] = (x[n] * (1 + acc/max(cnt,1))) @ projW + projb.
// ---------------------------------------------------------------------------
__global__ __launch_bounds__(256) void phase1_node(
    const float* __restrict__ x, const float* __restrict__ acc1,
    const int* __restrict__ cntI, const float* __restrict__ Wp,
    const float* __restrict__ bp, float* __restrict__ h,
    unsigned short* __restrict__ hb, int N)
{
  __shared__ float s0[4][20];
  const int t = threadIdx.x;
  const int nb = blockIdx.x << 2;
  if (t < 68) {
    int nl = t / 17, c = t % 17;
    int n = nb + nl;
    float v = 0.0f;
    if (n < N) {
      float cnt = fmaxf((float)cntI[n], 1.0f);
      v = x[n * 17 + c] * (1.0f + acc1[n * 17 + c] / cnt);
    }
    s0[nl][c] = v;
  }
  __syncthreads();
  int nl = t >> 6, j = t & 63;
  int n = nb + nl;
  if (n < N) {
    float acc = bp[j];
#pragma unroll
    for (int c = 0; c < 17; c++) acc = fmaf(s0[nl][c], Wp[c * 64 + j], acc);
    h[n * 64 + j] = acc;
    hb[n * 64 + j] = f2bf(acc);
  }
}

// ---------------------------------------------------------------------------
// Weight prep (phase2): bf16-convert + transpose smp weights.
// ---------------------------------------------------------------------------
__global__ __launch_bounds__(256) void prep_w(
    const float* __restrict__ sW1, const float* __restrict__ sW2,
    unsigned short* __restrict__ W1t, unsigned short* __restrict__ W2t)
{
  int i = blockIdx.x * 256 + threadIdx.x;
  if (i < 2 * 64 * 128) {
    int l = i >> 13; int r = i & 8191; int n = r >> 7; int k = r & 127;
    W1t[i] = f2bf(sW1[((size_t)l * 128 + k) * 64 + n]);
  }
  if (i < 2 * 64 * 64) {
    int l = i >> 12; int r = i & 4095; int n = r >> 6; int k = r & 63;
    W2t[i] = f2bf(sW2[((size_t)l * 64 + k) * 64 + n]);
  }
}

// ---------------------------------------------------------------------------
// Phase 2 edge kernel (MFMA, all weights in registers — R5 config):
// 64-edge tiles (sorted by dst), 256 threads = 4 waves, bounds(256,3).
// ---------------------------------------------------------------------------
__global__ __launch_bounds__(256, 3) void phase2_edge(
    const unsigned short* __restrict__ hb, const int2* __restrict__ pairS,
    const unsigned short* __restrict__ W1t, const float* __restrict__ b1,
    const unsigned short* __restrict__ W2t, const float* __restrict__ b2,
    float* __restrict__ accum, int E, int ntiles)
{
  __shared__ unsigned short sA[64][136];    // A-tile; aliased as f32[64][68] later
  __shared__ unsigned short sHid[64][72];
  __shared__ int   sDst[64];
  float* sRedF = (float*)&sA[0][0];         // 64 x 68 f32

  const int t = threadIdx.x;
  const int wv   = t >> 6;
  const int lane = t & 63;
  const int l16  = lane & 15;
  const int quad = lane >> 4;

  // loop-invariant weight fragments + biases -> registers
  s16x8 w1f[4][4], w2f[4][2];
  float bias1[4], bias2[4];
#pragma unroll
  for (int cb = 0; cb < 4; cb++) {
    const int n = cb * 16 + l16;
#pragma unroll
    for (int kb = 0; kb < 4; kb++)
      w1f[cb][kb] = *(const s16x8*)&W1t[n * 128 + kb * 32 + quad * 8];
#pragma unroll
    for (int kb = 0; kb < 2; kb++)
      w2f[cb][kb] = *(const s16x8*)&W2t[n * 64 + kb * 32 + quad * 8];
    bias1[cb] = b1[n];
    bias2[cb] = b2[n];
  }

  for (int tile = blockIdx.x; tile < ntiles; tile += gridDim.x) {
    const int eb = tile << 6;

    // stage A: row r = sorted edge eb+r; cols 0..63 = h[dst], 64..127 = h[src]
#pragma unroll
    for (int i = 0; i < 4; i++) {
      int g = t + i * 256; int r = g >> 4, c = g & 15;
      int er = eb + r; if (er >= E) er = E - 1;
      int2 p = pairS[er];
      int node = (c >= 8) ? p.y : p.x;
      if (c == 0) sDst[r] = p.x;
      *(uint4*)&sA[r][c * 8] = *(const uint4*)&hb[(size_t)node * 64 + (c & 7) * 8];
    }
    __syncthreads();                               // 1

    // pass 1: hidden = relu([h_i|h_j] @ W1 + b1)
    f32x4 acc[4];
#pragma unroll
    for (int cb = 0; cb < 4; cb++)
      acc[cb] = (f32x4){bias1[cb], bias1[cb], bias1[cb], bias1[cb]};
#pragma unroll
    for (int kb = 0; kb < 4; kb++) {
      s16x8 aF = *(const s16x8*)&sA[wv * 16 + l16][kb * 32 + quad * 8];
#pragma unroll
      for (int cb = 0; cb < 4; cb++)
        acc[cb] = __builtin_amdgcn_mfma_f32_16x16x32_bf16(aF, w1f[cb][kb], acc[cb], 0, 0, 0);
    }
#pragma unroll
    for (int cb = 0; cb < 4; cb++)
#pragma unroll
      for (int reg = 0; reg < 4; reg++)
        sHid[wv * 16 + quad * 4 + reg][cb * 16 + l16] = f2bf(fmaxf(acc[cb][reg], 0.0f));
    __syncthreads();                               // 2 (all sA reads done)

    // pass 2: u = hidden @ W2 + b2
#pragma unroll
    for (int cb = 0; cb < 4; cb++)
      acc[cb] = (f32x4){bias2[cb], bias2[cb], bias2[cb], bias2[cb]};
#pragma unroll
    for (int kb = 0; kb < 2; kb++) {
      s16x8 aF = *(const s16x8*)&sHid[wv * 16 + l16][kb * 32 + quad * 8];
#pragma unroll
      for (int cb = 0; cb < 4; cb++)
        acc[cb] = __builtin_amdgcn_mfma_f32_16x16x32_bf16(aF, w2f[cb][kb], acc[cb], 0, 0, 0);
    }

    // f = 2*tanh(u)-1 -> sRed (f32, aliases sA; safe after barrier 2)
#pragma unroll
    for (int cb = 0; cb < 4; cb++)
#pragma unroll
      for (int reg = 0; reg < 4; reg++) {
        int row = wv * 16 + quad * 4 + reg;
        float f = (eb + row < E) ? tanh_factor(acc[cb][reg]) : 0.0f;
        sRedF[row * 68 + cb * 16 + l16] = f;
      }
    __syncthreads();                               // 3

    // wave-uniform segmented walk: thread owns col j, rows r0..r0+15
    {
      int j = t & 63;
      int r0 = (t >> 6) * 16;
      float run = 0.0f;
      int cur = sDst[r0];
#pragma unroll
      for (int k = 0; k < 16; k++) {
        int r = r0 + k;
        int d = sDst[r];                 // wave-uniform
        float v = sRedF[r * 68 + j];
        if (d != cur) {                  // wave-uniform branch
          atomic_add_f32(&accum[(size_t)cur * 64 + j], run);
          run = 0.0f; cur = d;
        }
        run += v;
      }
      atomic_add_f32(&accum[(size_t)cur * 64 + j], run);
    }
    __syncthreads();                               // 4: sA/sDst reuse
  }
}

// ---------------------------------------------------------------------------
// Node update + BN statistics: h = h * (1 + acc/cnt); accumulate sum/sumsq.
// ---------------------------------------------------------------------------
__global__ __launch_bounds__(256) void node_update_bn(
    float* __restrict__ h, const float* __restrict__ accum,
    const int* __restrict__ cntI, float* __restrict__ bns,
    float* __restrict__ bnq, int N)
{
  const int t = threadIdx.x;
  float ls = 0.0f, lq = 0.0f;
  int total = N * 64;
  for (int idx = blockIdx.x * 256 + t; idx < total; idx += gridDim.x * 256) {
    int n = idx >> 6;
    float cnt = fmaxf((float)cntI[n], 1.0f);
    float v = h[idx] * (1.0f + accum[idx] / cnt);
    h[idx] = v;
    ls += v; lq += v * v;
  }
  __shared__ float ss[256], sq[256];
  ss[t] = ls; sq[t] = lq;
  __syncthreads();
  if (t < 64) {
    float s = ss[t] + ss[t + 64] + ss[t + 128] + ss[t + 192];
    float q = sq[t] + sq[t + 64] + sq[t + 128] + sq[t + 192];
    atomic_add_f32(&bns[t], s);
    atomic_add_f32(&bnq[t], q);
  }
}

// ---------------------------------------------------------------------------
// BN apply + relu (in place); optional bf16 mirror for next MFMA layer.
// ---------------------------------------------------------------------------
__global__ __launch_bounds__(256) void bn_apply_relu(
    float* __restrict__ d, const float* __restrict__ bns,
    const float* __restrict__ bnq, const float* __restrict__ gam,
    const float* __restrict__ bet, unsigned short* __restrict__ hbOut,
    int total, int cmask, float invRows)
{
  for (int idx = blockIdx.x * 256 + threadIdx.x; idx < total;
       idx += gridDim.x * 256) {
    int c = idx & cmask;
    float m = bns[c] * invRows;
    float var = bnq[c] * invRows - m * m;
    float sc = gam[c] * rsqrtf(var + 1e-5f);
    float v = fmaxf((d[idx] - m) * sc + bet[c], 0.0f);
    d[idx] = v;
    if (hbOut) hbOut[idx] = f2bf(v);
  }
}

// ---------------------------------------------------------------------------
// Classifier matmul (rows x K @ K x C) + bias, with BN stats.
// ---------------------------------------------------------------------------
__global__ __launch_bounds__(256) void clf_mm_bn(
    const float* __restrict__ in, const float* __restrict__ W,
    const float* __restrict__ b, float* __restrict__ out,
    float* __restrict__ bns, float* __restrict__ bnq,
    int rows, int K, int cshift)
{
  const int t = threadIdx.x;
  const int C = 1 << cshift;
  int total = rows << cshift;
  float ls = 0.0f, lq = 0.0f;
  for (int idx = blockIdx.x * 256 + t; idx < total; idx += gridDim.x * 256) {
    int n = idx >> cshift;
    int c = idx & (C - 1);
    float acc = b[c];
#pragma unroll 8
    for (int k = 0; k < K; k++) acc = fmaf(in[n * K + k], W[(k << cshift) + c], acc);
    out[idx] = acc;
    ls += acc; lq += acc * acc;
  }
  __shared__ float ss[256], sq[256];
  ss[t] = ls; sq[t] = lq;
  __syncthreads();
  if (t < C) {
    float s = 0.0f, q = 0.0f;
    for (int i = t; i < 256; i += C) { s += ss[i]; q += sq[i]; }
    atomic_add_f32(&bns[t], s);
    atomic_add_f32(&bnq[t], q);
  }
}

__global__ __launch_bounds__(256) void clf_final(
    const float* __restrict__ z2, const float* __restrict__ W3,
    const float* __restrict__ b3, float* __restrict__ out, int rows)
{
  int n = blockIdx.x * 256 + threadIdx.x;
  if (n >= rows) return;
  float acc = b3[0];
#pragma unroll
  for (int k = 0; k < 32; k++) acc = fmaf(z2[n * 32 + k], W3[k], acc);
  out[n] = acc;
}

// ---------------------------------------------------------------------------
extern "C" void kernel_launch(void* const* d_in, const int* in_sizes, int n_in,
                              void* d_out, int out_size, void* d_ws, size_t ws_size,
                              hipStream_t stream)
{
  const float* x    = (const float*)d_in[0];
  const int*   ei   = (const int*)  d_in[1];
  const float* dts  = (const float*)d_in[2];
  const float* freq = (const float*)d_in[4];
  const float* phs  = (const float*)d_in[5];
  const float* tW1  = (const float*)d_in[6];
  const float* tb1  = (const float*)d_in[7];
  const float* tW2  = (const float*)d_in[8];
  const float* tb2  = (const float*)d_in[9];
  const float* pW   = (const float*)d_in[10];
  const float* pb   = (const float*)d_in[11];
  const float* sW1  = (const float*)d_in[12];
  const float* sb1  = (const float*)d_in[13];
  const float* sW2  = (const float*)d_in[14];
  const float* sb2  = (const float*)d_in[15];
  const float* bng  = (const float*)d_in[16];
  const float* bnb  = (const float*)d_in[17];
  const float* cW1  = (const float*)d_in[18];
  const float* cb1  = (const float*)d_in[19];
  const float* cg1  = (const float*)d_in[20];
  const float* cbb1 = (const float*)d_in[21];
  const float* cW2  = (const float*)d_in[22];
  const float* cb2  = (const float*)d_in[23];
  const float* cg2  = (const float*)d_in[24];
  const float* cbb2 = (const float*)d_in[25];
  const float* cW3  = (const float*)d_in[26];
  const float* cb3  = (const float*)d_in[27];
  float* out = (float*)d_out;

  const int N = in_sizes[0] / 17;
  const int E = in_sizes[1] / 2;
  const int B = out_size;

  // workspace layout
  float* ws     = (float*)d_ws;
  float* h      = ws;                            // N*64
  float* acc2   = h    + (size_t)N * 64;         // N*64
  float* acc1   = acc2 + (size_t)N * 64;         // N*17 (z1/z2 alias)
  float* z1     = acc1;
  float* z2     = z1 + (size_t)B * 64;
  float* bns    = acc1 + (size_t)N * 17;         // 64
  float* bnq    = bns + 64;                      // 64
  unsigned short* hb  = (unsigned short*)(bnq + 64);   // N*64 bf16
  unsigned short* W1t = hb + (size_t)N * 64;           // 2*64*128
  unsigned short* W2t = W1t + 2 * 64 * 128;            // 2*64*64
  int*   cntI   = (int*)(W2t + 2 * 64 * 64);     // N
  int*   cursor = cntI + N;                      // N
  int*   bsum   = cursor + N;                    // 512
  int2*  pairS  = (int2*)(bsum + 512);           // E (dst,src)
  float* dtsS   = (float*)(pairS + (size_t)E);   // E
  unsigned short* xb   = (unsigned short*)(dtsS + (size_t)E);  // N*24
  unsigned short* W1t1 = xb + (size_t)N * 24;    // 48*96
  unsigned short* W2t1 = W1t1 + 48 * 96;         // 32*64
  size_t needed = (size_t)((char*)(W2t1 + 32 * 64) - (char*)d_ws);
  if (ws_size < needed) return;  // fail visibly (output stays poisoned)

  const int ntiles = (E + 63) / 64;
  const int NB = (N + 255) / 256;
  if (NB > 512) return;

  // ---- counting sort by dst (also yields counts) + weight/x prep ----
  hipMemsetAsync(cntI, 0, (size_t)N * 4, stream);
  hipMemsetAsync(acc1, 0, (size_t)N * 17 * 4, stream);
  k_hist<<<(E + 255) / 256, 256, 0, stream>>>(ei, cntI, E);
  k_scan_block<<<NB, 256, 0, stream>>>(cntI, cursor, bsum, N);
  k_scan_bsum<<<1, 512, 0, stream>>>(bsum, NB);
  k_scan_add<<<NB, 256, 0, stream>>>(cursor, bsum, N);
  k_scatter<<<(E + 255) / 256, 256, 0, stream>>>(ei, dts, cursor, pairS, dtsS, E);
  prep_w<<<64, 256, 0, stream>>>(sW1, sW2, W1t, W2t);
  prep1<<<(N * 24 + 255) / 256, 256, 0, stream>>>(x, tW1, tW2, xb, W1t1, W2t1, N);

  // ---- phase 1 ----
  phase1_edge_mfma<<<1024, 256, 0, stream>>>(
      xb, pairS, dtsS, freq, phs, W1t1, tb1, W2t1, tb2, acc1, E, ntiles);
  phase1_node<<<(N + 3) / 4, 256, 0, stream>>>(x, acc1, cntI, pW, pb, h, hb, N);

  // ---- phase 2: L = 2 message-passing + BN layers ----
  for (int l = 0; l < 2; l++) {
    hipMemsetAsync(acc2, 0, (size_t)N * 64 * 4, stream);
    hipMemsetAsync(bns, 0, 128 * 4, stream);
    phase2_edge<<<768, 256, 0, stream>>>(
        hb, pairS, W1t + (size_t)l * 64 * 128, sb1 + l * 64,
        W2t + (size_t)l * 64 * 64, sb2 + l * 64, acc2, E, ntiles);
    node_update_bn<<<1024, 256, 0, stream>>>(h, acc2, cntI, bns, bnq, N);
    bn_apply_relu<<<2048, 256, 0, stream>>>(
        h, bns, bnq, bng + l * 64, bnb + l * 64, hb, N * 64, 63, 1.0f / (float)N);
  }

  // ---- classifier on first B rows of h ----
  hipMemsetAsync(bns, 0, 128 * 4, stream);
  clf_mm_bn<<<2500, 256, 0, stream>>>(h, cW1, cb1, z1, bns, bnq, B, 64, 6);
  bn_apply_relu<<<1024, 256, 0, stream>>>(z1, bns, bnq, cg1, cbb1, nullptr,
                                          B * 64, 63, 1.0f / (float)B);
  hipMemsetAsync(bns, 0, 128 * 4, stream);
  clf_mm_bn<<<1250, 256, 0, stream>>>(z1, cW2, cb2, z2, bns, bnq, B, 64, 5);
  bn_apply_relu<<<512, 256, 0, stream>>>(z2, bns, bnq, cg2, cbb2, nullptr,
                                         B * 32, 31, 1.0f / (float)B);
  clf_final<<<(B + 255) / 256, 256, 0, stream>>>(z2, cW3, cb3, out, B);
}

// Round 9
// 908.232 us; speedup vs baseline: 1.6035x; 1.1272x over previous
//
#include <hip/hip_runtime.h>
#include <hip/hip_bf16.h>

// ---------------------------------------------------------------------------
// THEGCNModel — R9: factor phase2 pass-1 out of the edge loop.
//   hidden = relu([h_i|h_j]@W1 + b1) = relu(P1[dst] + P2[src]) with
//   P1 = h@W1a + b1, P2 = h@W1b computed ONCE per node (prep_P dense MFMA,
//   0.82 GMAC vs 13.1 GMAC recomputed per-edge before — 16x dedup via sort).
//   phase2_edge: gather P1/P2, build hidden B-frags in registers (no sHid
//   round-trip), operand-swapped single MFMA pass (W2 as A, 32 VGPR frags,
//   no remat risk at bounds(256,4)), 2 barriers/tile, LDS 17.7KB -> 4 blk/CU.
// ---------------------------------------------------------------------------

typedef float  f32x4 __attribute__((ext_vector_type(4)));
typedef short  s16x8 __attribute__((ext_vector_type(8)));

__device__ __forceinline__ float tanh_factor(float u) {
  float e = __expf(2.0f * u);          // 2*tanh(u)-1 == 1 - 4/(exp(2u)+1)
  return 1.0f - 4.0f / (e + 1.0f);
}

__device__ __forceinline__ void atomic_add_f32(float* p, float v) {
  unsafeAtomicAdd(p, v);               // native global_atomic_add_f32
}

__device__ __forceinline__ unsigned short f2bf(float f) {
  __hip_bfloat16 b = __float2bfloat16(f);
  return *(unsigned short*)&b;
}
__device__ __forceinline__ float bf2f(unsigned short u) {
  unsigned int v = ((unsigned int)u) << 16;
  return *(float*)&v;
}

// ---------------------------------------------------------------------------
// Counting sort by dst: histogram -> 2-level exclusive scan -> scatter.
// ---------------------------------------------------------------------------
__global__ __launch_bounds__(256) void k_hist(
    const int* __restrict__ ei, int* __restrict__ cntI, int E)
{
  int e = blockIdx.x * 256 + threadIdx.x;
  if (e < E) atomicAdd(&cntI[ei[E + e]], 1);
}

__global__ __launch_bounds__(256) void k_scan_block(
    const int* __restrict__ cntI, int* __restrict__ cursor,
    int* __restrict__ bsum, int N)
{
  __shared__ int s[256];
  const int t = threadIdx.x;
  int i = blockIdx.x * 256 + t;
  int v = (i < N) ? cntI[i] : 0;
  s[t] = v;
  for (int off = 1; off < 256; off <<= 1) {
    __syncthreads();
    int x = (t >= off) ? s[t - off] : 0;
    __syncthreads();
    s[t] += x;
  }
  __syncthreads();
  if (i < N) cursor[i] = s[t] - v;          // local exclusive
  if (t == 255) bsum[blockIdx.x] = s[255];
}

__global__ __launch_bounds__(512) void k_scan_bsum(int* __restrict__ bsum, int nb)
{
  __shared__ int s[512];
  const int t = threadIdx.x;
  int v = (t < nb) ? bsum[t] : 0;
  s[t] = v;
  for (int off = 1; off < 512; off <<= 1) {
    __syncthreads();
    int x = (t >= off) ? s[t - off] : 0;
    __syncthreads();
    s[t] += x;
  }
  __syncthreads();
  if (t < nb) bsum[t] = s[t] - v;           // exclusive
}

__global__ __launch_bounds__(256) void k_scan_add(
    int* __restrict__ cursor, const int* __restrict__ bsum, int N)
{
  int i = blockIdx.x * 256 + threadIdx.x;
  if (i < N) cursor[i] += bsum[blockIdx.x];
}

__global__ __launch_bounds__(256) void k_scatter(
    const int* __restrict__ ei, const float* __restrict__ dts,
    int* __restrict__ cursor, int2* __restrict__ pairS,
    float* __restrict__ dtsS, int E)
{
  int e = blockIdx.x * 256 + threadIdx.x;
  if (e >= E) return;
  int d = ei[E + e];
  int pos = atomicAdd(&cursor[d], 1);
  pairS[pos] = make_int2(d, ei[e]);
  dtsS[pos] = dts[e];
}

// ---------------------------------------------------------------------------
// prep1: xb = bf16(x) padded to 24 cols; W1t1[n:48][k:96], W2t1[n:32][k:64]
// transposed+padded phase-1 MLP weights.
// ---------------------------------------------------------------------------
__global__ __launch_bounds__(256) void prep1(
    const float* __restrict__ x, const float* __restrict__ tW1,
    const float* __restrict__ tW2, unsigned short* __restrict__ xb,
    unsigned short* __restrict__ W1t1, unsigned short* __restrict__ W2t1, int N)
{
  int i = blockIdx.x * 256 + threadIdx.x;
  int totalX = N * 24;
  for (int idx = i; idx < totalX; idx += gridDim.x * 256) {
    int n = idx / 24, c = idx - n * 24;
    xb[idx] = (c < 17) ? f2bf(x[n * 17 + c]) : (unsigned short)0;
  }
  if (i < 48 * 96) {
    int n = i / 96, k = i - n * 96;
    int src = (k < 17) ? k : (k >= 24 && k < 41) ? (k - 24 + 17)
            : (k >= 48 && k < 80) ? (k - 48 + 34) : -1;
    W1t1[i] = (n < 33 && src >= 0) ? f2bf(tW1[src * 33 + n]) : (unsigned short)0;
  }
  if (i < 32 * 64) {
    int n = i / 64, k = i - n * 64;
    W2t1[i] = (n < 17 && k < 33) ? f2bf(tW2[k * 17 + n]) : (unsigned short)0;
  }
}

// ---------------------------------------------------------------------------
// Phase 1 edge kernel (MFMA) — unchanged from R8.
// ---------------------------------------------------------------------------
__global__ __launch_bounds__(256, 3) void phase1_edge_mfma(
    const unsigned short* __restrict__ xb, const int2* __restrict__ pairS,
    const float* __restrict__ dtsS, const float* __restrict__ freq,
    const float* __restrict__ phs,
    const unsigned short* __restrict__ W1t1, const float* __restrict__ b1,
    const unsigned short* __restrict__ W2t1, const float* __restrict__ b2,
    float* __restrict__ accum, int E, int ntiles)
{
  __shared__ unsigned short sA[64][104];
  __shared__ unsigned short sHid[64][72];
  __shared__ float sRed[64][20];
  __shared__ int   sDst[64];

  const int t = threadIdx.x;
  const int wv = t >> 6, lane = t & 63, l16 = lane & 15, quad = lane >> 4;

  s16x8 w1f[3][3], w2f[2][2];
  float bias1[3], bias2[2];
#pragma unroll
  for (int cb = 0; cb < 3; cb++) {
    int n = cb * 16 + l16;
#pragma unroll
    for (int kb = 0; kb < 3; kb++)
      w1f[cb][kb] = *(const s16x8*)&W1t1[n * 96 + kb * 32 + quad * 8];
    bias1[cb] = (n < 33) ? b1[n] : 0.0f;
  }
#pragma unroll
  for (int cb = 0; cb < 2; cb++) {
    int n = cb * 16 + l16;
#pragma unroll
    for (int kb = 0; kb < 2; kb++)
      w2f[cb][kb] = *(const s16x8*)&W2t1[n * 64 + kb * 32 + quad * 8];
    bias2[cb] = (n < 17) ? b2[n] : 0.0f;
  }

  for (int i = t; i < 64 * 28; i += 256) {
    int r = i / 28, c = i - r * 28;
    int col = (c < 6) ? 18 + c : (c < 12) ? 42 + (c - 6) : 80 + (c - 12);
    sA[r][col] = 0;
  }
  for (int i = t; i < 64 * 16; i += 256) {
    int r = i >> 4, c = 48 + (i & 15);
    sHid[r][c] = 0;
  }

  for (int tile = blockIdx.x; tile < ntiles; tile += gridDim.x) {
    const int eb = tile << 6;

    {
      int e_l = t >> 2, q = t & 3;
      int er = eb + e_l; if (er >= E) er = E - 1;
      if (q < 2) {
        int2 p = pairS[er];
        int node = q ? p.y : p.x;
        if (!q) sDst[e_l] = p.x;
        const unsigned short* src = &xb[(size_t)node * 24];
        int base = q ? 24 : 0;
        *(uint4*)&sA[e_l][base]     = *(const uint4*)&src[0];
        *(uint4*)&sA[e_l][base + 8] = *(const uint4*)&src[8];
        *(unsigned int*)&sA[e_l][base + 16] = *(const unsigned int*)&src[16];
      } else {
        float dt = dtsS[er];
        int k0 = (q == 2) ? 0 : 16;
        unsigned short tmp[16] __attribute__((aligned(16)));
#pragma unroll
        for (int j = 0; j < 16; j++)
          tmp[j] = f2bf(__cosf(fmaf(dt, freq[k0 + j], phs[k0 + j])));
        *(uint4*)&sA[e_l][48 + k0]     = *(const uint4*)&tmp[0];
        *(uint4*)&sA[e_l][48 + k0 + 8] = *(const uint4*)&tmp[8];
      }
    }
    __syncthreads();                               // 1

    f32x4 a1[3];
#pragma unroll
    for (int cb = 0; cb < 3; cb++)
      a1[cb] = (f32x4){bias1[cb], bias1[cb], bias1[cb], bias1[cb]};
#pragma unroll
    for (int kb = 0; kb < 3; kb++) {
      s16x8 aF = *(const s16x8*)&sA[wv * 16 + l16][kb * 32 + quad * 8];
#pragma unroll
      for (int cb = 0; cb < 3; cb++)
        a1[cb] = __builtin_amdgcn_mfma_f32_16x16x32_bf16(aF, w1f[cb][kb], a1[cb], 0, 0, 0);
    }
#pragma unroll
    for (int cb = 0; cb < 3; cb++)
#pragma unroll
      for (int reg = 0; reg < 4; reg++)
        sHid[wv * 16 + quad * 4 + reg][cb * 16 + l16] = f2bf(fmaxf(a1[cb][reg], 0.0f));
    __syncthreads();                               // 2

    f32x4 a2[2];
#pragma unroll
    for (int cb = 0; cb < 2; cb++)
      a2[cb] = (f32x4){bias2[cb], bias2[cb], bias2[cb], bias2[cb]};
#pragma unroll
    for (int kb = 0; kb < 2; kb++) {
      s16x8 aF = *(const s16x8*)&sHid[wv * 16 + l16][kb * 32 + quad * 8];
#pragma unroll
      for (int cb = 0; cb < 2; cb++)
        a2[cb] = __builtin_amdgcn_mfma_f32_16x16x32_bf16(aF, w2f[cb][kb], a2[cb], 0, 0, 0);
    }

#pragma unroll
    for (int reg = 0; reg < 4; reg++) {
      int row = wv * 16 + quad * 4 + reg;
      bool ok = (eb + row < E);
      sRed[row][l16] = ok ? tanh_factor(a2[0][reg]) : 0.0f;
      if (l16 == 0) sRed[row][16] = ok ? tanh_factor(a2[1][reg]) : 0.0f;
    }
    __syncthreads();                               // 3

    if (t < 68) {
      int col = t % 17;
      int r0 = (t / 17) * 16;
      float run = 0.0f;
      int cur = sDst[r0];
#pragma unroll
      for (int k = 0; k < 16; k++) {
        int r = r0 + k;
        int d = sDst[r];
        float v = sRed[r][col];
        if (d != cur) {
          atomic_add_f32(&accum[(size_t)cur * 17 + col], run);
          run = 0.0f; cur = d;
        }
        run += v;
      }
      atomic_add_f32(&accum[(size_t)cur * 17 + col], run);
    }
    __syncthreads();                               // 4
  }
}

// ---------------------------------------------------------------------------
// Phase 1 node kernel: h[n] = (x[n] * (1 + acc/max(cnt,1))) @ projW + projb.
// (bf16 mirror removed — prep_P reads f32 h directly)
// ---------------------------------------------------------------------------
__global__ __launch_bounds__(256) void phase1_node(
    const float* __restrict__ x, const float* __restrict__ acc1,
    const int* __restrict__ cntI, const float* __restrict__ Wp,
    const float* __restrict__ bp, float* __restrict__ h, int N)
{
  __shared__ float s0[4][20];
  const int t = threadIdx.x;
  const int nb = blockIdx.x << 2;
  if (t < 68) {
    int nl = t / 17, c = t % 17;
    int n = nb + nl;
    float v = 0.0f;
    if (n < N) {
      float cnt = fmaxf((float)cntI[n], 1.0f);
      v = x[n * 17 + c] * (1.0f + acc1[n * 17 + c] / cnt);
    }
    s0[nl][c] = v;
  }
  __syncthreads();
  int nl = t >> 6, j = t & 63;
  int n = nb + nl;
  if (n < N) {
    float acc = bp[j];
#pragma unroll
    for (int c = 0; c < 17; c++) acc = fmaf(s0[nl][c], Wp[c * 64 + j], acc);
    h[n * 64 + j] = acc;
  }
}

// ---------------------------------------------------------------------------
// Weight prep (phase2): bf16-convert + transpose smp weights.
// ---------------------------------------------------------------------------
__global__ __launch_bounds__(256) void prep_w(
    const float* __restrict__ sW1, const float* __restrict__ sW2,
    unsigned short* __restrict__ W1t, unsigned short* __restrict__ W2t)
{
  int i = blockIdx.x * 256 + threadIdx.x;
  if (i < 2 * 64 * 128) {
    int l = i >> 13; int r = i & 8191; int n = r >> 7; int k = r & 127;
    W1t[i] = f2bf(sW1[((size_t)l * 128 + k) * 64 + n]);
  }
  if (i < 2 * 64 * 64) {
    int l = i >> 12; int r = i & 4095; int n = r >> 6; int k = r & 63;
    W2t[i] = f2bf(sW2[((size_t)l * 64 + k) * 64 + n]);
  }
}

// ---------------------------------------------------------------------------
// prep_P: dense per-node pass-1. P1[n] = h[n]@W1a + b1, P2[n] = h[n]@W1b.
// One 64-node tile per block; operand-swapped MFMA (W1 as A) so each thread
// holds one node and 4 consecutive output cols -> 8B coalesced-ish stores.
// ---------------------------------------------------------------------------
__global__ void prep_P(
    const float* __restrict__ h, const unsigned short* __restrict__ W1t,
    const float* __restrict__ b1, unsigned short* __restrict__ P1,
    unsigned short* __restrict__ P2, int N)
{
  __shared__ unsigned short sH[64][72];
  const int t = threadIdx.x;
  const int wv = t >> 6, lane = t & 63, l16 = lane & 15, quad = lane >> 4;
  const int nb = blockIdx.x << 6;

  // stage 64x64 f32 -> bf16 LDS tile
#pragma unroll
  for (int i = 0; i < 4; i++) {
    int g = t + i * 256;
    int r = g >> 4, c4 = (g & 15) << 2;
    int n = nb + r; if (n >= N) n = N - 1;
    float4 v = *(const float4*)&h[(size_t)n * 64 + c4];
    ushort4 o = { f2bf(v.x), f2bf(v.y), f2bf(v.z), f2bf(v.w) };
    *(ushort4*)&sH[r][c4] = o;
  }
  __syncthreads();

  const int n = nb + wv * 16 + l16;
#pragma unroll
  for (int half = 0; half < 2; half++) {
    f32x4 acc[4];
#pragma unroll
    for (int cb = 0; cb < 4; cb++) {
      if (half == 0) {
        float4 bv = *(const float4*)&b1[cb * 16 + quad * 4];
        acc[cb] = (f32x4){bv.x, bv.y, bv.z, bv.w};
      } else {
        acc[cb] = (f32x4){0.0f, 0.0f, 0.0f, 0.0f};
      }
    }
#pragma unroll
    for (int kb = 0; kb < 2; kb++) {
      s16x8 bF = *(const s16x8*)&sH[wv * 16 + l16][kb * 32 + quad * 8];
#pragma unroll
      for (int cb = 0; cb < 4; cb++) {
        s16x8 aF = *(const s16x8*)&W1t[(cb * 16 + l16) * 128 + half * 64 + kb * 32 + quad * 8];
        acc[cb] = __builtin_amdgcn_mfma_f32_16x16x32_bf16(aF, bF, acc[cb], 0, 0, 0);
      }
    }
    if (n < N) {
      unsigned short* P = half ? P2 : P1;
#pragma unroll
      for (int cb = 0; cb < 4; cb++) {
        ushort4 o = { f2bf(acc[cb][0]), f2bf(acc[cb][1]),
                      f2bf(acc[cb][2]), f2bf(acc[cb][3]) };
        *(ushort4*)&P[(size_t)n * 64 + cb * 16 + quad * 4] = o;
      }
    }
  }
}

// ---------------------------------------------------------------------------
// Phase 2 edge kernel (single operand-swapped MFMA pass):
// hidden frag built in registers from gathered P1[dst]+P2[src]; u^T = W2t·hid;
// thread holds one edge x 16 cols; vectorized f32x4 epilogue into own-wave
// LDS rows (same-wave ordering, no barrier); wave-local segmented walk.
// 2 barriers/tile; LDS 17.7KB; W2 frags = 32 VGPR (no remat risk at cap 128).
// ---------------------------------------------------------------------------
__global__ __launch_bounds__(256, 4) void phase2_edge(
    const unsigned short* __restrict__ P1, const unsigned short* __restrict__ P2,
    const int2* __restrict__ pairS,
    const unsigned short* __restrict__ W2t, const float* __restrict__ b2,
    float* __restrict__ accum, int E, int ntiles)
{
  __shared__ unsigned short sA[64][136];   // [edge][0:64]=P1[dst], [64:128]=P2[src]
  __shared__ int sDst[64];
  float* sRedF = (float*)&sA[0][0];        // aliased 64x68 f32 (same 17408B)

  const int t = threadIdx.x;
  const int wv = t >> 6, lane = t & 63, l16 = lane & 15, quad = lane >> 4;

  // W2 as A-operand fragments (32 VGPR) + bias vectors
  s16x8 w2f[4][2];
  f32x4 bias2v[4];
#pragma unroll
  for (int cb = 0; cb < 4; cb++) {
#pragma unroll
    for (int kb = 0; kb < 2; kb++)
      w2f[cb][kb] = *(const s16x8*)&W2t[(cb * 16 + l16) * 64 + kb * 32 + quad * 8];
    float4 bv = *(const float4*)&b2[cb * 16 + quad * 4];
    bias2v[cb] = (f32x4){bv.x, bv.y, bv.z, bv.w};
  }

  const int eRow = wv * 16 + l16;          // this thread's edge row in tile

  for (int tile = blockIdx.x; tile < ntiles; tile += gridDim.x) {
    const int eb = tile << 6;

    // stage: row r = sorted edge; cols 0..63 = P1[dst], 64..127 = P2[src]
#pragma unroll
    for (int i = 0; i < 4; i++) {
      int g = t + i * 256; int r = g >> 4, c = g & 15;
      int er = eb + r; if (er >= E) er = E - 1;
      int2 p = pairS[er];
      int node = (c >= 8) ? p.y : p.x;
      if (c == 0) sDst[r] = p.x;
      const unsigned short* src = (c >= 8) ? P2 : P1;
      *(uint4*)&sA[r][c * 8] = *(const uint4*)&src[(size_t)node * 64 + (c & 7) * 8];
    }
    __syncthreads();                       // 1

    // hidden B-frags for this thread's edge: relu(P1+P2), packed bf16
    s16x8 hidf[2];
#pragma unroll
    for (int kb = 0; kb < 2; kb++) {
      s16x8 x1 = *(const s16x8*)&sA[eRow][kb * 32 + quad * 8];
      s16x8 x2 = *(const s16x8*)&sA[eRow][64 + kb * 32 + quad * 8];
      s16x8 hf;
#pragma unroll
      for (int j = 0; j < 8; j++) {
        float a = bf2f((unsigned short)x1[j]);
        float b = bf2f((unsigned short)x2[j]);
        hf[j] = (short)f2bf(fmaxf(a + b, 0.0f));
      }
      hidf[kb] = hf;
    }

    // u^T[n2][edge] = W2t @ hidden^T + b2
    f32x4 acc[4];
#pragma unroll
    for (int cb = 0; cb < 4; cb++) acc[cb] = bias2v[cb];
#pragma unroll
    for (int kb = 0; kb < 2; kb++)
#pragma unroll
      for (int cb = 0; cb < 4; cb++)
        acc[cb] = __builtin_amdgcn_mfma_f32_16x16x32_bf16(w2f[cb][kb], hidf[kb], acc[cb], 0, 0, 0);

    // epilogue: f = 2*tanh(u)-1 -> sRedF, own-wave rows only (no barrier:
    // same-wave LDS ordering; all sA reads for these rows already done)
    bool ok = (eb + eRow < E);
#pragma unroll
    for (int cb = 0; cb < 4; cb++) {
      f32x4 f;
#pragma unroll
      for (int reg = 0; reg < 4; reg++)
        f[reg] = ok ? tanh_factor(acc[cb][reg]) : 0.0f;
      *(f32x4*)&sRedF[eRow * 68 + cb * 16 + quad * 4] = f;
    }

    // wave-local segmented walk: lane = col, rows = own wave's 16 edges
    {
      int j = lane;
      int r0 = wv * 16;
      float run = 0.0f;
      int cur = sDst[r0];
#pragma unroll
      for (int k = 0; k < 16; k++) {
        int r = r0 + k;
        int d = sDst[r];                 // wave-uniform
        float v = sRedF[r * 68 + j];
        if (d != cur) {                  // wave-uniform branch
          atomic_add_f32(&accum[(size_t)cur * 64 + j], run);
          run = 0.0f; cur = d;
        }
        run += v;
      }
      atomic_add_f32(&accum[(size_t)cur * 64 + j], run);
    }
    __syncthreads();                     // 2: protect sA/sDst/sRedF for next tile
  }
}

// ---------------------------------------------------------------------------
// Node update + BN statistics: h = h * (1 + acc/cnt); accumulate sum/sumsq.
// ---------------------------------------------------------------------------
__global__ __launch_bounds__(256) void node_update_bn(
    float* __restrict__ h, const float* __restrict__ accum,
    const int* __restrict__ cntI, float* __restrict__ bns,
    float* __restrict__ bnq, int N)
{
  const int t = threadIdx.x;
  float ls = 0.0f, lq = 0.0f;
  int total = N * 64;
  for (int idx = blockIdx.x * 256 + t; idx < total; idx += gridDim.x * 256) {
    int n = idx >> 6;
    float cnt = fmaxf((float)cntI[n], 1.0f);
    float v = h[idx] * (1.0f + accum[idx] / cnt);
    h[idx] = v;
    ls += v; lq += v * v;
  }
  __shared__ float ss[256], sq[256];
  ss[t] = ls; sq[t] = lq;
  __syncthreads();
  if (t < 64) {
    float s = ss[t] + ss[t + 64] + ss[t + 128] + ss[t + 192];
    float q = sq[t] + sq[t + 64] + sq[t + 128] + sq[t + 192];
    atomic_add_f32(&bns[t], s);
    atomic_add_f32(&bnq[t], q);
  }
}

// ---------------------------------------------------------------------------
// BN apply + relu (in place).
// ---------------------------------------------------------------------------
__global__ __launch_bounds__(256) void bn_apply_relu(
    float* __restrict__ d, const float* __restrict__ bns,
    const float* __restrict__ bnq, const float* __restrict__ gam,
    const float* __restrict__ bet, int total, int cmask, float invRows)
{
  for (int idx = blockIdx.x * 256 + threadIdx.x; idx < total;
       idx += gridDim.x * 256) {
    int c = idx & cmask;
    float m = bns[c] * invRows;
    float var = bnq[c] * invRows - m * m;
    float sc = gam[c] * rsqrtf(var + 1e-5f);
    d[idx] = fmaxf((d[idx] - m) * sc + bet[c], 0.0f);
  }
}

// ---------------------------------------------------------------------------
// Classifier matmul (rows x K @ K x C) + bias, with BN stats.
// ---------------------------------------------------------------------------
__global__ __launch_bounds__(256) void clf_mm_bn(
    const float* __restrict__ in, const float* __restrict__ W,
    const float* __restrict__ b, float* __restrict__ out,
    float* __restrict__ bns, float* __restrict__ bnq,
    int rows, int K, int cshift)
{
  const int t = threadIdx.x;
  const int C = 1 << cshift;
  int total = rows << cshift;
  float ls = 0.0f, lq = 0.0f;
  for (int idx = blockIdx.x * 256 + t; idx < total; idx += gridDim.x * 256) {
    int n = idx >> cshift;
    int c = idx & (C - 1);
    float acc = b[c];
#pragma unroll 8
    for (int k = 0; k < K; k++) acc = fmaf(in[n * K + k], W[(k << cshift) + c], acc);
    out[idx] = acc;
    ls += acc; lq += acc * acc;
  }
  __shared__ float ss[256], sq[256];
  ss[t] = ls; sq[t] = lq;
  __syncthreads();
  if (t < C) {
    float s = 0.0f, q = 0.0f;
    for (int i = t; i < 256; i += C) { s += ss[i]; q += sq[i]; }
    atomic_add_f32(&bns[t], s);
    atomic_add_f32(&bnq[t], q);
  }
}

__global__ __launch_bounds__(256) void clf_final(
    const float* __restrict__ z2, const float* __restrict__ W3,
    const float* __restrict__ b3, float* __restrict__ out, int rows)
{
  int n = blockIdx.x * 256 + threadIdx.x;
  if (n >= rows) return;
  float acc = b3[0];
#pragma unroll
  for (int k = 0; k < 32; k++) acc = fmaf(z2[n * 32 + k], W3[k], acc);
  out[n] = acc;
}

// ---------------------------------------------------------------------------
extern "C" void kernel_launch(void* const* d_in, const int* in_sizes, int n_in,
                              void* d_out, int out_size, void* d_ws, size_t ws_size,
                              hipStream_t stream)
{
  const float* x    = (const float*)d_in[0];
  const int*   ei   = (const int*)  d_in[1];
  const float* dts  = (const float*)d_in[2];
  const float* freq = (const float*)d_in[4];
  const float* phs  = (const float*)d_in[5];
  const float* tW1  = (const float*)d_in[6];
  const float* tb1  = (const float*)d_in[7];
  const float* tW2  = (const float*)d_in[8];
  const float* tb2  = (const float*)d_in[9];
  const float* pW   = (const float*)d_in[10];
  const float* pb   = (const float*)d_in[11];
  const float* sW1  = (const float*)d_in[12];
  const float* sb1  = (const float*)d_in[13];
  const float* sW2  = (const float*)d_in[14];
  const float* sb2  = (const float*)d_in[15];
  const float* bng  = (const float*)d_in[16];
  const float* bnb  = (const float*)d_in[17];
  const float* cW1  = (const float*)d_in[18];
  const float* cb1  = (const float*)d_in[19];
  const float* cg1  = (const float*)d_in[20];
  const float* cbb1 = (const float*)d_in[21];
  const float* cW2  = (const float*)d_in[22];
  const float* cb2  = (const float*)d_in[23];
  const float* cg2  = (const float*)d_in[24];
  const float* cbb2 = (const float*)d_in[25];
  const float* cW3  = (const float*)d_in[26];
  const float* cb3  = (const float*)d_in[27];
  float* out = (float*)d_out;

  const int N = in_sizes[0] / 17;
  const int E = in_sizes[1] / 2;
  const int B = out_size;

  // workspace layout (f32 slots unless noted)
  float* ws     = (float*)d_ws;
  float* h      = ws;                            // N*64
  float* acc2   = h    + (size_t)N * 64;         // N*64
  float* acc1   = acc2 + (size_t)N * 64;         // N*17 (z1/z2 alias)
  float* z1     = acc1;
  float* z2     = z1 + (size_t)B * 64;
  float* bns    = acc1 + (size_t)N * 17;         // 64
  float* bnq    = bns + 64;                      // 64
  unsigned short* W1t = (unsigned short*)(bnq + 64);   // 2*64*128
  unsigned short* W2t = W1t + 2 * 64 * 128;            // 2*64*64
  int*   cntI   = (int*)(W2t + 2 * 64 * 64);     // N
  int*   cursor = cntI + N;                      // N
  int*   bsum   = cursor + N;                    // 512
  int2*  pairS  = (int2*)(bsum + 512);           // E (dst,src)
  // region1: dtsS (E) + xb (N*24 bf16), later ALIASED by P1 (N*64 bf16)
  float* dtsS   = (float*)(pairS + (size_t)E);
  unsigned short* xb = (unsigned short*)(dtsS + (size_t)E);  // N*24
  unsigned short* P1 = (unsigned short*)dtsS;                // N*64 (alias)
  size_t r1a = (size_t)E + ((size_t)N * 24 + 1) / 2;         // dtsS+xb f32 slots
  size_t r1b = ((size_t)N * 64 + 1) / 2;                     // P1 f32 slots
  size_t r1  = r1a > r1b ? r1a : r1b;
  unsigned short* P2   = (unsigned short*)(dtsS + r1);       // N*64 bf16
  unsigned short* W1t1 = P2 + (size_t)N * 64;                // 48*96
  unsigned short* W2t1 = W1t1 + 48 * 96;                     // 32*64
  size_t needed = (size_t)((char*)(W2t1 + 32 * 64) - (char*)d_ws);
  if (ws_size < needed) return;  // fail visibly (output stays poisoned)

  const int ntiles = (E + 63) / 64;
  const int NB = (N + 255) / 256;
  if (NB > 512) return;

  // ---- counting sort by dst (also yields counts) + weight/x prep ----
  hipMemsetAsync(cntI, 0, (size_t)N * 4, stream);
  hipMemsetAsync(acc1, 0, (size_t)N * 17 * 4, stream);
  k_hist<<<(E + 255) / 256, 256, 0, stream>>>(ei, cntI, E);
  k_scan_block<<<NB, 256, 0, stream>>>(cntI, cursor, bsum, N);
  k_scan_bsum<<<1, 512, 0, stream>>>(bsum, NB);
  k_scan_add<<<NB, 256, 0, stream>>>(cursor, bsum, N);
  k_scatter<<<(E + 255) / 256, 256, 0, stream>>>(ei, dts, cursor, pairS, dtsS, E);
  prep_w<<<64, 256, 0, stream>>>(sW1, sW2, W1t, W2t);
  prep1<<<(N * 24 + 255) / 256, 256, 0, stream>>>(x, tW1, tW2, xb, W1t1, W2t1, N);

  // ---- phase 1 ----
  phase1_edge_mfma<<<1024, 256, 0, stream>>>(
      xb, pairS, dtsS, freq, phs, W1t1, tb1, W2t1, tb2, acc1, E, ntiles);
  phase1_node<<<(N + 3) / 4, 256, 0, stream>>>(x, acc1, cntI, pW, pb, h, N);

  // ---- phase 2: L = 2 message-passing + BN layers ----
  for (int l = 0; l < 2; l++) {
    prep_P<<<(N + 63) / 64, 256, 0, stream>>>(
        h, W1t + (size_t)l * 64 * 128, sb1 + l * 64, P1, P2, N);
    hipMemsetAsync(acc2, 0, (size_t)N * 64 * 4, stream);
    hipMemsetAsync(bns, 0, 128 * 4, stream);
    phase2_edge<<<1024, 256, 0, stream>>>(
        P1, P2, pairS, W2t + (size_t)l * 64 * 64, sb2 + l * 64, acc2, E, ntiles);
    node_update_bn<<<1024, 256, 0, stream>>>(h, acc2, cntI, bns, bnq, N);
    bn_apply_relu<<<2048, 256, 0, stream>>>(
        h, bns, bnq, bng + l * 64, bnb + l * 64, N * 64, 63, 1.0f / (float)N);
  }

  // ---- classifier on first B rows of h ----
  hipMemsetAsync(bns, 0, 128 * 4, stream);
  clf_mm_bn<<<2500, 256, 0, stream>>>(h, cW1, cb1, z1, bns, bnq, B, 64, 6);
  bn_apply_relu<<<1024, 256, 0, stream>>>(z1, bns, bnq, cg1, cbb1,
                                          B * 64, 63, 1.0f / (float)B);
  hipMemsetAsync(bns, 0, 128 * 4, stream);
  clf_mm_bn<<<1250, 256, 0, stream>>>(z1, cW2, cb2, z2, bns, bnq, B, 64, 5);
  bn_apply_relu<<<512, 256, 0, stream>>>(z2, bns, bnq, cg2, cbb2,
                                         B * 32, 31, 1.0f / (float)B);
  clf_final<<<(B + 255) / 256, 256, 0, stream>>>(z2, cW3, cb3, out, B);
}

// Round 10
// 894.328 us; speedup vs baseline: 1.6284x; 1.0155x over previous
//
#include <hip/hip_runtime.h>
#include <hip/hip_bf16.h>

// ---------------------------------------------------------------------------
// THEGCNModel — R10:
//   * k_scatter: one scattered 8B store/edge (src,dts packed); dstS produced
//     by coalesced k_expand from rowPtr (R9 evidence: 150MB WRITE for 19MB
//     payload = 2 scattered lines/edge).
//   * phase1/phase2 edge kernels: barrier-free wave-private 16-edge tiles —
//     every LDS row is staged, computed and walked by one wave (same-wave DS
//     ordering, proven in R9's epilogue->walk path). Zero __syncthreads in
//     the tile loop; cheaper staging (4 lanes/edge, 64B contiguous per lane).
// ---------------------------------------------------------------------------

typedef float  f32x4 __attribute__((ext_vector_type(4)));
typedef short  s16x8 __attribute__((ext_vector_type(8)));

__device__ __forceinline__ float tanh_factor(float u) {
  float e = __expf(2.0f * u);          // 2*tanh(u)-1 == 1 - 4/(exp(2u)+1)
  return 1.0f - 4.0f / (e + 1.0f);
}

__device__ __forceinline__ void atomic_add_f32(float* p, float v) {
  unsafeAtomicAdd(p, v);               // native global_atomic_add_f32
}

__device__ __forceinline__ unsigned short f2bf(float f) {
  __hip_bfloat16 b = __float2bfloat16(f);
  return *(unsigned short*)&b;
}
__device__ __forceinline__ float bf2f(unsigned short u) {
  unsigned int v = ((unsigned int)u) << 16;
  return *(float*)&v;
}

// ---------------------------------------------------------------------------
// Counting sort by dst: histogram -> scan -> expand(dstS) -> scatter(src,dts).
// ---------------------------------------------------------------------------
__global__ __launch_bounds__(256) void k_hist(
    const int* __restrict__ ei, int* __restrict__ cntI, int E)
{
  int e = blockIdx.x * 256 + threadIdx.x;
  if (e < E) atomicAdd(&cntI[ei[E + e]], 1);
}

__global__ __launch_bounds__(256) void k_scan_block(
    const int* __restrict__ cntI, int* __restrict__ cursor,
    int* __restrict__ bsum, int N)
{
  __shared__ int s[256];
  const int t = threadIdx.x;
  int i = blockIdx.x * 256 + t;
  int v = (i < N) ? cntI[i] : 0;
  s[t] = v;
  for (int off = 1; off < 256; off <<= 1) {
    __syncthreads();
    int x = (t >= off) ? s[t - off] : 0;
    __syncthreads();
    s[t] += x;
  }
  __syncthreads();
  if (i < N) cursor[i] = s[t] - v;          // local exclusive
  if (t == 255) bsum[blockIdx.x] = s[255];
}

__global__ __launch_bounds__(512) void k_scan_bsum(int* __restrict__ bsum, int nb)
{
  __shared__ int s[512];
  const int t = threadIdx.x;
  int v = (t < nb) ? bsum[t] : 0;
  s[t] = v;
  for (int off = 1; off < 512; off <<= 1) {
    __syncthreads();
    int x = (t >= off) ? s[t - off] : 0;
    __syncthreads();
    s[t] += x;
  }
  __syncthreads();
  if (t < nb) bsum[t] = s[t] - v;           // exclusive
}

__global__ __launch_bounds__(256) void k_scan_add(
    int* __restrict__ cursor, const int* __restrict__ bsum, int N)
{
  int i = blockIdx.x * 256 + threadIdx.x;
  if (i < N) cursor[i] += bsum[blockIdx.x];
}

// dstS[rowPtr[n] .. rowPtr[n]+cnt[n]) = n  — coalesced sequential writes.
__global__ __launch_bounds__(256) void k_expand(
    const int* __restrict__ cursor, const int* __restrict__ cntI,
    int* __restrict__ dstS, int N)
{
  int n = blockIdx.x * 256 + threadIdx.x;
  if (n >= N) return;
  int s = cursor[n], c = cntI[n];
  for (int i = 0; i < c; i++) dstS[s + i] = n;
}

__global__ __launch_bounds__(256) void k_scatter(
    const int* __restrict__ ei, const float* __restrict__ dts,
    int* __restrict__ cursor, int2* __restrict__ srcdtS, int E)
{
  int e = blockIdx.x * 256 + threadIdx.x;
  if (e >= E) return;
  int d = ei[E + e];
  int pos = atomicAdd(&cursor[d], 1);
  srcdtS[pos] = make_int2(ei[e], __float_as_int(dts[e]));
}

// ---------------------------------------------------------------------------
// prep1: xb = bf16(x) padded to 24 cols; W1t1[n:48][k:96], W2t1[n:32][k:64].
// ---------------------------------------------------------------------------
__global__ __launch_bounds__(256) void prep1(
    const float* __restrict__ x, const float* __restrict__ tW1,
    const float* __restrict__ tW2, unsigned short* __restrict__ xb,
    unsigned short* __restrict__ W1t1, unsigned short* __restrict__ W2t1, int N)
{
  int i = blockIdx.x * 256 + threadIdx.x;
  int totalX = N * 24;
  for (int idx = i; idx < totalX; idx += gridDim.x * 256) {
    int n = idx / 24, c = idx - n * 24;
    xb[idx] = (c < 17) ? f2bf(x[n * 17 + c]) : (unsigned short)0;
  }
  if (i < 48 * 96) {
    int n = i / 96, k = i - n * 96;
    int src = (k < 17) ? k : (k >= 24 && k < 41) ? (k - 24 + 17)
            : (k >= 48 && k < 80) ? (k - 48 + 34) : -1;
    W1t1[i] = (n < 33 && src >= 0) ? f2bf(tW1[src * 33 + n]) : (unsigned short)0;
  }
  if (i < 32 * 64) {
    int n = i / 64, k = i - n * 64;
    W2t1[i] = (n < 17 && k < 33) ? f2bf(tW2[k * 17 + n]) : (unsigned short)0;
  }
}

// ---------------------------------------------------------------------------
// Phase 1 edge kernel (MFMA, barrier-free wave-private 16-edge tiles).
// ---------------------------------------------------------------------------
__global__ __launch_bounds__(256, 3) void phase1_edge_mfma(
    const unsigned short* __restrict__ xb, const int* __restrict__ dstS,
    const int2* __restrict__ srcdtS, const float* __restrict__ freq,
    const float* __restrict__ phs,
    const unsigned short* __restrict__ W1t1, const float* __restrict__ b1,
    const unsigned short* __restrict__ W2t1, const float* __restrict__ b2,
    float* __restrict__ accum, int E, int nwt)
{
  __shared__ unsigned short sA[64][104];
  __shared__ unsigned short sHid[64][72];
  __shared__ float sRed[64][20];
  __shared__ int   sDst[64];

  const int t = threadIdx.x;
  const int wv = t >> 6, lane = t & 63, l16 = lane & 15, quad = lane >> 4;
  const int r0 = wv * 16;

  s16x8 w1f[3][3], w2f[2][2];
  float bias1[3], bias2[2];
#pragma unroll
  for (int cb = 0; cb < 3; cb++) {
    int n = cb * 16 + l16;
#pragma unroll
    for (int kb = 0; kb < 3; kb++)
      w1f[cb][kb] = *(const s16x8*)&W1t1[n * 96 + kb * 32 + quad * 8];
    bias1[cb] = (n < 33) ? b1[n] : 0.0f;
  }
#pragma unroll
  for (int cb = 0; cb < 2; cb++) {
    int n = cb * 16 + l16;
#pragma unroll
    for (int kb = 0; kb < 2; kb++)
      w2f[cb][kb] = *(const s16x8*)&W2t1[n * 64 + kb * 32 + quad * 8];
    bias2[cb] = (n < 17) ? b2[n] : 0.0f;
  }

  // zero own-wave pad columns once
  for (int i = lane; i < 16 * 28; i += 64) {
    int rr = r0 + i / 28, c = i % 28;
    int col = (c < 6) ? 18 + c : (c < 12) ? 42 + (c - 6) : 80 + (c - 12);
    sA[rr][col] = 0;
  }
  for (int i = lane; i < 256; i += 64)
    sHid[r0 + (i >> 4)][48 + (i & 15)] = 0;

  const int gw = blockIdx.x * 4 + wv;
  const int nw = gridDim.x * 4;

  for (int tile = gw; tile < nwt; tile += nw) {
    const int eb = tile << 4;

    // staging: 4 lanes/edge (q0 xi, q1 xj, q2/q3 rel halves) — own rows only
    {
      int e_loc = lane >> 2, q = lane & 3;
      int rr = r0 + e_loc;
      int er = eb + e_loc; if (er >= E) er = E - 1;
      if (q < 2) {
        int node = q ? srcdtS[er].x : dstS[er];
        if (!q) sDst[rr] = node;
        const unsigned short* src = &xb[(size_t)node * 24];
        int base = q ? 24 : 0;
        *(uint4*)&sA[rr][base]     = *(const uint4*)&src[0];
        *(uint4*)&sA[rr][base + 8] = *(const uint4*)&src[8];
        *(unsigned int*)&sA[rr][base + 16] = *(const unsigned int*)&src[16];
      } else {
        float dt = __int_as_float(srcdtS[er].y);
        int k0 = (q == 2) ? 0 : 16;
        unsigned short tmp[16] __attribute__((aligned(16)));
#pragma unroll
        for (int j = 0; j < 16; j++)
          tmp[j] = f2bf(__cosf(fmaf(dt, freq[k0 + j], phs[k0 + j])));
        *(uint4*)&sA[rr][48 + k0]     = *(const uint4*)&tmp[0];
        *(uint4*)&sA[rr][48 + k0 + 8] = *(const uint4*)&tmp[8];
      }
    }

    // pass1: hid = relu(A @ W1 + b1)   (own row r0+l16)
    f32x4 a1[3];
#pragma unroll
    for (int cb = 0; cb < 3; cb++)
      a1[cb] = (f32x4){bias1[cb], bias1[cb], bias1[cb], bias1[cb]};
#pragma unroll
    for (int kb = 0; kb < 3; kb++) {
      s16x8 aF = *(const s16x8*)&sA[r0 + l16][kb * 32 + quad * 8];
#pragma unroll
      for (int cb = 0; cb < 3; cb++)
        a1[cb] = __builtin_amdgcn_mfma_f32_16x16x32_bf16(aF, w1f[cb][kb], a1[cb], 0, 0, 0);
    }
#pragma unroll
    for (int cb = 0; cb < 3; cb++)
#pragma unroll
      for (int reg = 0; reg < 4; reg++)
        sHid[r0 + quad * 4 + reg][cb * 16 + l16] = f2bf(fmaxf(a1[cb][reg], 0.0f));

    // pass2: u = hid @ W2 + b2
    f32x4 a2[2];
#pragma unroll
    for (int cb = 0; cb < 2; cb++)
      a2[cb] = (f32x4){bias2[cb], bias2[cb], bias2[cb], bias2[cb]};
#pragma unroll
    for (int kb = 0; kb < 2; kb++) {
      s16x8 aF = *(const s16x8*)&sHid[r0 + l16][kb * 32 + quad * 8];
#pragma unroll
      for (int cb = 0; cb < 2; cb++)
        a2[cb] = __builtin_amdgcn_mfma_f32_16x16x32_bf16(aF, w2f[cb][kb], a2[cb], 0, 0, 0);
    }

    // f -> sRed (own rows)
#pragma unroll
    for (int reg = 0; reg < 4; reg++) {
      int row = r0 + quad * 4 + reg;
      bool ok = (eb + quad * 4 + reg < E);
      sRed[row][l16] = ok ? tanh_factor(a2[0][reg]) : 0.0f;
      if (l16 == 0) sRed[row][16] = ok ? tanh_factor(a2[1][reg]) : 0.0f;
    }

    // wave-local segmented walk: lanes 0..16, col = lane, own 16 rows
    if (lane < 17) {
      int col = lane;
      float run = 0.0f;
      int cur = sDst[r0];
#pragma unroll
      for (int k = 0; k < 16; k++) {
        int d = sDst[r0 + k];
        float v = sRed[r0 + k][col];
        if (d != cur) {
          atomic_add_f32(&accum[(size_t)cur * 17 + col], run);
          run = 0.0f; cur = d;
        }
        run += v;
      }
      atomic_add_f32(&accum[(size_t)cur * 17 + col], run);
    }
  }
}

// ---------------------------------------------------------------------------
// Phase 1 node kernel: h[n] = (x[n] * (1 + acc/max(cnt,1))) @ projW + projb.
// ---------------------------------------------------------------------------
__global__ __launch_bounds__(256) void phase1_node(
    const float* __restrict__ x, const float* __restrict__ acc1,
    const int* __restrict__ cntI, const float* __restrict__ Wp,
    const float* __restrict__ bp, float* __restrict__ h, int N)
{
  __shared__ float s0[4][20];
  const int t = threadIdx.x;
  const int nb = blockIdx.x << 2;
  if (t < 68) {
    int nl = t / 17, c = t % 17;
    int n = nb + nl;
    float v = 0.0f;
    if (n < N) {
      float cnt = fmaxf((float)cntI[n], 1.0f);
      v = x[n * 17 + c] * (1.0f + acc1[n * 17 + c] / cnt);
    }
    s0[nl][c] = v;
  }
  __syncthreads();
  int nl = t >> 6, j = t & 63;
  int n = nb + nl;
  if (n < N) {
    float acc = bp[j];
#pragma unroll
    for (int c = 0; c < 17; c++) acc = fmaf(s0[nl][c], Wp[c * 64 + j], acc);
    h[n * 64 + j] = acc;
  }
}

// ---------------------------------------------------------------------------
// Weight prep (phase2): bf16-convert + transpose smp weights.
// ---------------------------------------------------------------------------
__global__ __launch_bounds__(256) void prep_w(
    const float* __restrict__ sW1, const float* __restrict__ sW2,
    unsigned short* __restrict__ W1t, unsigned short* __restrict__ W2t)
{
  int i = blockIdx.x * 256 + threadIdx.x;
  if (i < 2 * 64 * 128) {
    int l = i >> 13; int r = i & 8191; int n = r >> 7; int k = r & 127;
    W1t[i] = f2bf(sW1[((size_t)l * 128 + k) * 64 + n]);
  }
  if (i < 2 * 64 * 64) {
    int l = i >> 12; int r = i & 4095; int n = r >> 6; int k = r & 63;
    W2t[i] = f2bf(sW2[((size_t)l * 64 + k) * 64 + n]);
  }
}

// ---------------------------------------------------------------------------
// prep_P: P1[n] = h[n]@W1a + b1, P2[n] = h[n]@W1b (dense per-node, MFMA).
// ---------------------------------------------------------------------------
__global__ void prep_P(
    const float* __restrict__ h, const unsigned short* __restrict__ W1t,
    const float* __restrict__ b1, unsigned short* __restrict__ P1,
    unsigned short* __restrict__ P2, int N)
{
  __shared__ unsigned short sH[64][72];
  const int t = threadIdx.x;
  const int wv = t >> 6, lane = t & 63, l16 = lane & 15, quad = lane >> 4;
  const int nb = blockIdx.x << 6;

#pragma unroll
  for (int i = 0; i < 4; i++) {
    int g = t + i * 256;
    int r = g >> 4, c4 = (g & 15) << 2;
    int n = nb + r; if (n >= N) n = N - 1;
    float4 v = *(const float4*)&h[(size_t)n * 64 + c4];
    ushort4 o = { f2bf(v.x), f2bf(v.y), f2bf(v.z), f2bf(v.w) };
    *(ushort4*)&sH[r][c4] = o;
  }
  __syncthreads();

  const int n = nb + wv * 16 + l16;
#pragma unroll
  for (int half = 0; half < 2; half++) {
    f32x4 acc[4];
#pragma unroll
    for (int cb = 0; cb < 4; cb++) {
      if (half == 0) {
        float4 bv = *(const float4*)&b1[cb * 16 + quad * 4];
        acc[cb] = (f32x4){bv.x, bv.y, bv.z, bv.w};
      } else {
        acc[cb] = (f32x4){0.0f, 0.0f, 0.0f, 0.0f};
      }
    }
#pragma unroll
    for (int kb = 0; kb < 2; kb++) {
      s16x8 bF = *(const s16x8*)&sH[wv * 16 + l16][kb * 32 + quad * 8];
#pragma unroll
      for (int cb = 0; cb < 4; cb++) {
        s16x8 aF = *(const s16x8*)&W1t[(cb * 16 + l16) * 128 + half * 64 + kb * 32 + quad * 8];
        acc[cb] = __builtin_amdgcn_mfma_f32_16x16x32_bf16(aF, bF, acc[cb], 0, 0, 0);
      }
    }
    if (n < N) {
      unsigned short* P = half ? P2 : P1;
#pragma unroll
      for (int cb = 0; cb < 4; cb++) {
        ushort4 o = { f2bf(acc[cb][0]), f2bf(acc[cb][1]),
                      f2bf(acc[cb][2]), f2bf(acc[cb][3]) };
        *(ushort4*)&P[(size_t)n * 64 + cb * 16 + quad * 4] = o;
      }
    }
  }
}

// ---------------------------------------------------------------------------
// Phase 2 edge kernel — barrier-free wave-private 16-edge tiles.
// hidden = relu(P1[dst]+P2[src]) built in registers; u^T = W2t @ hidden^T.
// ---------------------------------------------------------------------------
__global__ __launch_bounds__(256, 4) void phase2_edge(
    const unsigned short* __restrict__ P1, const unsigned short* __restrict__ P2,
    const int* __restrict__ dstS, const int2* __restrict__ srcdtS,
    const unsigned short* __restrict__ W2t, const float* __restrict__ b2,
    float* __restrict__ accum, int E, int nwt)
{
  __shared__ unsigned short sA[64][136];   // [edge][0:64]=P1[dst], [64:128]=P2[src]
  __shared__ int sDst[64];
  float* sRedF = (float*)&sA[0][0];        // aliased 64x68 f32 (same stride 272B)

  const int t = threadIdx.x;
  const int wv = t >> 6, lane = t & 63, l16 = lane & 15, quad = lane >> 4;
  const int r0 = wv * 16;

  s16x8 w2f[4][2];
  f32x4 bias2v[4];
#pragma unroll
  for (int cb = 0; cb < 4; cb++) {
#pragma unroll
    for (int kb = 0; kb < 2; kb++)
      w2f[cb][kb] = *(const s16x8*)&W2t[(cb * 16 + l16) * 64 + kb * 32 + quad * 8];
    float4 bv = *(const float4*)&b2[cb * 16 + quad * 4];
    bias2v[cb] = (f32x4){bv.x, bv.y, bv.z, bv.w};
  }

  const int gw = blockIdx.x * 4 + wv;
  const int nw = gridDim.x * 4;
  const int eRow = r0 + l16;

  for (int tile = gw; tile < nwt; tile += nw) {
    const int eb = tile << 4;

    // staging: 4 lanes/edge, 64B contiguous per lane, own rows only
    {
      int e_loc = lane >> 2, q = lane & 3;
      int rr = r0 + e_loc;
      int er = eb + e_loc; if (er >= E) er = E - 1;
      int node;
      if (q < 2) { node = dstS[er]; if (!q) sDst[rr] = node; }
      else       node = srcdtS[er].x;
      const unsigned short* src = (q < 2 ? P1 : P2) + (size_t)node * 64 + (q & 1) * 32;
      int cb0 = q * 32;
#pragma unroll
      for (int j = 0; j < 4; j++)
        *(uint4*)&sA[rr][cb0 + j * 8] = *(const uint4*)&src[j * 8];
    }

    // hidden B-frags: relu(P1+P2), packed bf16 (own row)
    s16x8 hidf[2];
#pragma unroll
    for (int kb = 0; kb < 2; kb++) {
      s16x8 x1 = *(const s16x8*)&sA[eRow][kb * 32 + quad * 8];
      s16x8 x2 = *(const s16x8*)&sA[eRow][64 + kb * 32 + quad * 8];
      s16x8 hf;
#pragma unroll
      for (int j = 0; j < 8; j++) {
        float a = bf2f((unsigned short)x1[j]);
        float b = bf2f((unsigned short)x2[j]);
        hf[j] = (short)f2bf(fmaxf(a + b, 0.0f));
      }
      hidf[kb] = hf;
    }

    // u^T[n2][edge] = W2t @ hidden^T + b2
    f32x4 acc[4];
#pragma unroll
    for (int cb = 0; cb < 4; cb++) acc[cb] = bias2v[cb];
#pragma unroll
    for (int kb = 0; kb < 2; kb++)
#pragma unroll
      for (int cb = 0; cb < 4; cb++)
        acc[cb] = __builtin_amdgcn_mfma_f32_16x16x32_bf16(w2f[cb][kb], hidf[kb], acc[cb], 0, 0, 0);

    // f = 2*tanh(u)-1 -> sRedF (own rows; same-wave ordering)
    bool ok = (eb + l16 < E);
#pragma unroll
    for (int cb = 0; cb < 4; cb++) {
      f32x4 f;
#pragma unroll
      for (int reg = 0; reg < 4; reg++)
        f[reg] = ok ? tanh_factor(acc[cb][reg]) : 0.0f;
      *(f32x4*)&sRedF[eRow * 68 + cb * 16 + quad * 4] = f;
    }

    // wave-local segmented walk: lane = col, own 16 rows
    {
      float run = 0.0f;
      int cur = sDst[r0];
#pragma unroll
      for (int k = 0; k < 16; k++) {
        int d = sDst[r0 + k];                 // wave-uniform
        float v = sRedF[(r0 + k) * 68 + lane];
        if (d != cur) {                       // wave-uniform branch
          atomic_add_f32(&accum[(size_t)cur * 64 + lane], run);
          run = 0.0f; cur = d;
        }
        run += v;
      }
      atomic_add_f32(&accum[(size_t)cur * 64 + lane], run);
    }
  }
}

// ---------------------------------------------------------------------------
// Node update + BN statistics: h = h * (1 + acc/cnt); accumulate sum/sumsq.
// ---------------------------------------------------------------------------
__global__ __launch_bounds__(256) void node_update_bn(
    float* __restrict__ h, const float* __restrict__ accum,
    const int* __restrict__ cntI, float* __restrict__ bns,
    float* __restrict__ bnq, int N)
{
  const int t = threadIdx.x;
  float ls = 0.0f, lq = 0.0f;
  int total = N * 64;
  for (int idx = blockIdx.x * 256 + t; idx < total; idx += gridDim.x * 256) {
    int n = idx >> 6;
    float cnt = fmaxf((float)cntI[n], 1.0f);
    float v = h[idx] * (1.0f + accum[idx] / cnt);
    h[idx] = v;
    ls += v; lq += v * v;
  }
  __shared__ float ss[256], sq[256];
  ss[t] = ls; sq[t] = lq;
  __syncthreads();
  if (t < 64) {
    float s = ss[t] + ss[t + 64] + ss[t + 128] + ss[t + 192];
    float q = sq[t] + sq[t + 64] + sq[t + 128] + sq[t + 192];
    atomic_add_f32(&bns[t], s);
    atomic_add_f32(&bnq[t], q);
  }
}

// ---------------------------------------------------------------------------
// BN apply + relu (in place).
// ---------------------------------------------------------------------------
__global__ __launch_bounds__(256) void bn_apply_relu(
    float* __restrict__ d, const float* __restrict__ bns,
    const float* __restrict__ bnq, const float* __restrict__ gam,
    const float* __restrict__ bet, int total, int cmask, float invRows)
{
  for (int idx = blockIdx.x * 256 + threadIdx.x; idx < total;
       idx += gridDim.x * 256) {
    int c = idx & cmask;
    float m = bns[c] * invRows;
    float var = bnq[c] * invRows - m * m;
    float sc = gam[c] * rsqrtf(var + 1e-5f);
    d[idx] = fmaxf((d[idx] - m) * sc + bet[c], 0.0f);
  }
}

// ---------------------------------------------------------------------------
// Classifier matmul (rows x K @ K x C) + bias, with BN stats.
// ---------------------------------------------------------------------------
__global__ __launch_bounds__(256) void clf_mm_bn(
    const float* __restrict__ in, const float* __restrict__ W,
    const float* __restrict__ b, float* __restrict__ out,
    float* __restrict__ bns, float* __restrict__ bnq,
    int rows, int K, int cshift)
{
  const int t = threadIdx.x;
  const int C = 1 << cshift;
  int total = rows << cshift;
  float ls = 0.0f, lq = 0.0f;
  for (int idx = blockIdx.x * 256 + t; idx < total; idx += gridDim.x * 256) {
    int n = idx >> cshift;
    int c = idx & (C - 1);
    float acc = b[c];
#pragma unroll 8
    for (int k = 0; k < K; k++) acc = fmaf(in[n * K + k], W[(k << cshift) + c], acc);
    out[idx] = acc;
    ls += acc; lq += acc * acc;
  }
  __shared__ float ss[256], sq[256];
  ss[t] = ls; sq[t] = lq;
  __syncthreads();
  if (t < C) {
    float s = 0.0f, q = 0.0f;
    for (int i = t; i < 256; i += C) { s += ss[i]; q += sq[i]; }
    atomic_add_f32(&bns[t], s);
    atomic_add_f32(&bnq[t], q);
  }
}

__global__ __launch_bounds__(256) void clf_final(
    const float* __restrict__ z2, const float* __restrict__ W3,
    const float* __restrict__ b3, float* __restrict__ out, int rows)
{
  int n = blockIdx.x * 256 + threadIdx.x;
  if (n >= rows) return;
  float acc = b3[0];
#pragma unroll
  for (int k = 0; k < 32; k++) acc = fmaf(z2[n * 32 + k], W3[k], acc);
  out[n] = acc;
}

// ---------------------------------------------------------------------------
extern "C" void kernel_launch(void* const* d_in, const int* in_sizes, int n_in,
                              void* d_out, int out_size, void* d_ws, size_t ws_size,
                              hipStream_t stream)
{
  const float* x    = (const float*)d_in[0];
  const int*   ei   = (const int*)  d_in[1];
  const float* dts  = (const float*)d_in[2];
  const float* freq = (const float*)d_in[4];
  const float* phs  = (const float*)d_in[5];
  const float* tW1  = (const float*)d_in[6];
  const float* tb1  = (const float*)d_in[7];
  const float* tW2  = (const float*)d_in[8];
  const float* tb2  = (const float*)d_in[9];
  const float* pW   = (const float*)d_in[10];
  const float* pb   = (const float*)d_in[11];
  const float* sW1  = (const float*)d_in[12];
  const float* sb1  = (const float*)d_in[13];
  const float* sW2  = (const float*)d_in[14];
  const float* sb2  = (const float*)d_in[15];
  const float* bng  = (const float*)d_in[16];
  const float* bnb  = (const float*)d_in[17];
  const float* cW1  = (const float*)d_in[18];
  const float* cb1  = (const float*)d_in[19];
  const float* cg1  = (const float*)d_in[20];
  const float* cbb1 = (const float*)d_in[21];
  const float* cW2  = (const float*)d_in[22];
  const float* cb2  = (const float*)d_in[23];
  const float* cg2  = (const float*)d_in[24];
  const float* cbb2 = (const float*)d_in[25];
  const float* cW3  = (const float*)d_in[26];
  const float* cb3  = (const float*)d_in[27];
  float* out = (float*)d_out;

  const int N = in_sizes[0] / 17;
  const int E = in_sizes[1] / 2;
  const int B = out_size;

  // ---- workspace layout (byte offsets, union region for phase-local data) --
  char* base = (char*)d_ws;
  size_t off = 0;
  float* h    = (float*)(base + off); off += (size_t)N * 64 * 4;
  float* acc2 = (float*)(base + off); off += (size_t)N * 64 * 4;
  char*  uni  = base + off;           off += (size_t)N * 64 * 4;  // union
  float* bns  = (float*)(base + off); off += 64 * 4;
  float* bnq  = (float*)(base + off); off += 64 * 4;
  unsigned short* W1t = (unsigned short*)(base + off); off += 2 * 64 * 128 * 2;
  unsigned short* W2t = (unsigned short*)(base + off); off += 2 * 64 * 64 * 2;
  int* cntI   = (int*)(base + off); off += (size_t)N * 4;
  int* cursor = (int*)(base + off); off += (size_t)N * 4;
  int* bsum   = (int*)(base + off); off += 512 * 4;
  int* dstS   = (int*)(base + off); off += (size_t)E * 4;
  off = (off + 15) & ~(size_t)15;
  int2* srcdtS = (int2*)(base + off); off += (size_t)E * 8;
  size_t needed = off;
  if (ws_size < needed) return;  // fail visibly (output stays poisoned)

  // union members (phase1 | phase2 | classifier — lifetimes disjoint)
  float* acc1 = (float*)uni;                                     // N*17 f32
  unsigned short* xb   = (unsigned short*)(uni + (size_t)N * 17 * 4); // N*24
  unsigned short* W1t1 = xb + (size_t)N * 24;                    // 48*96
  unsigned short* W2t1 = W1t1 + 48 * 96;                         // 32*64
  unsigned short* P1 = (unsigned short*)uni;                     // N*64
  unsigned short* P2 = P1 + (size_t)N * 64;                      // N*64
  float* z1 = (float*)uni;                                       // B*64
  float* z2 = z1 + (size_t)B * 64;                               // B*32

  const int nwt = (E + 15) / 16;
  const int NB = (N + 255) / 256;
  if (NB > 512) return;

  // ---- counting sort by dst (yields counts + dstS) + weight/x prep ----
  hipMemsetAsync(cntI, 0, (size_t)N * 4, stream);
  hipMemsetAsync(acc1, 0, (size_t)N * 17 * 4, stream);
  k_hist<<<(E + 255) / 256, 256, 0, stream>>>(ei, cntI, E);
  k_scan_block<<<NB, 256, 0, stream>>>(cntI, cursor, bsum, N);
  k_scan_bsum<<<1, 512, 0, stream>>>(bsum, NB);
  k_scan_add<<<NB, 256, 0, stream>>>(cursor, bsum, N);
  k_expand<<<NB, 256, 0, stream>>>(cursor, cntI, dstS, N);   // before scatter!
  k_scatter<<<(E + 255) / 256, 256, 0, stream>>>(ei, dts, cursor, srcdtS, E);
  prep_w<<<64, 256, 0, stream>>>(sW1, sW2, W1t, W2t);
  prep1<<<(N * 24 + 255) / 256, 256, 0, stream>>>(x, tW1, tW2, xb, W1t1, W2t1, N);

  // ---- phase 1 ----
  phase1_edge_mfma<<<768, 256, 0, stream>>>(
      xb, dstS, srcdtS, freq, phs, W1t1, tb1, W2t1, tb2, acc1, E, nwt);
  phase1_node<<<(N + 3) / 4, 256, 0, stream>>>(x, acc1, cntI, pW, pb, h, N);

  // ---- phase 2: L = 2 message-passing + BN layers ----
  for (int l = 0; l < 2; l++) {
    prep_P<<<(N + 63) / 64, 256, 0, stream>>>(
        h, W1t + (size_t)l * 64 * 128, sb1 + l * 64, P1, P2, N);
    hipMemsetAsync(acc2, 0, (size_t)N * 64 * 4, stream);
    hipMemsetAsync(bns, 0, 128 * 4, stream);
    phase2_edge<<<1024, 256, 0, stream>>>(
        P1, P2, dstS, srcdtS, W2t + (size_t)l * 64 * 64, sb2 + l * 64,
        acc2, E, nwt);
    node_update_bn<<<1024, 256, 0, stream>>>(h, acc2, cntI, bns, bnq, N);
    bn_apply_relu<<<2048, 256, 0, stream>>>(
        h, bns, bnq, bng + l * 64, bnb + l * 64, N * 64, 63, 1.0f / (float)N);
  }

  // ---- classifier on first B rows of h ----
  hipMemsetAsync(bns, 0, 128 * 4, stream);
  clf_mm_bn<<<2500, 256, 0, stream>>>(h, cW1, cb1, z1, bns, bnq, B, 64, 6);
  bn_apply_relu<<<1024, 256, 0, stream>>>(z1, bns, bnq, cg1, cbb1,
                                          B * 64, 63, 1.0f / (float)B);
  hipMemsetAsync(bns, 0, 128 * 4, stream);
  clf_mm_bn<<<1250, 256, 0, stream>>>(z1, cW2, cb2, z2, bns, bnq, B, 64, 5);
  bn_apply_relu<<<512, 256, 0, stream>>>(z2, bns, bnq, cg2, cbb2,
                                         B * 32, 31, 1.0f / (float)B);
  clf_final<<<(B + 255) / 256, 256, 0, stream>>>(z2, cW3, cb3, out, B);
}

// Round 11
// 876.218 us; speedup vs baseline: 1.6621x; 1.0207x over previous
//
#include <hip/hip_runtime.h>
#include <hip/hip_bf16.h>

// ---------------------------------------------------------------------------
// THEGCNModel — R11 (on R10's barrier-free structure):
//   * tanh_factor: exact f32 div -> v_rcp_f32 (R10 evidence: phase2_edge
//     VALU-bound 60%, div chain ~10 VALU x16/thread/tile = biggest VALU item).
//   * dispatch trims: k_scan_add+k_expand fused; prep_w folded into prep1;
//     acc2 re-zeroed inside node_update_bn; single up-front memset for 8
//     ping-pong BN-stat slots (removes 4 mid-stream memsets).
// ---------------------------------------------------------------------------

typedef float  f32x4 __attribute__((ext_vector_type(4)));
typedef short  s16x8 __attribute__((ext_vector_type(8)));

__device__ __forceinline__ float tanh_factor(float u) {
  // 2*tanh(u)-1 == 1 - 4/(exp(2u)+1); rcp is 1-ulp approx (noise vs bf16)
  float e = __expf(2.0f * u);
  return fmaf(-4.0f, __builtin_amdgcn_rcpf(e + 1.0f), 1.0f);
}

__device__ __forceinline__ void atomic_add_f32(float* p, float v) {
  unsafeAtomicAdd(p, v);               // native global_atomic_add_f32
}

__device__ __forceinline__ unsigned short f2bf(float f) {
  __hip_bfloat16 b = __float2bfloat16(f);
  return *(unsigned short*)&b;
}
__device__ __forceinline__ float bf2f(unsigned short u) {
  unsigned int v = ((unsigned int)u) << 16;
  return *(float*)&v;
}

// ---------------------------------------------------------------------------
// Counting sort by dst: histogram -> scan -> expand(dstS) -> scatter(src,dts).
// ---------------------------------------------------------------------------
__global__ __launch_bounds__(256) void k_hist(
    const int* __restrict__ ei, int* __restrict__ cntI, int E)
{
  int e = blockIdx.x * 256 + threadIdx.x;
  if (e < E) atomicAdd(&cntI[ei[E + e]], 1);
}

__global__ __launch_bounds__(256) void k_scan_block(
    const int* __restrict__ cntI, int* __restrict__ cursor,
    int* __restrict__ bsum, int N)
{
  __shared__ int s[256];
  const int t = threadIdx.x;
  int i = blockIdx.x * 256 + t;
  int v = (i < N) ? cntI[i] : 0;
  s[t] = v;
  for (int off = 1; off < 256; off <<= 1) {
    __syncthreads();
    int x = (t >= off) ? s[t - off] : 0;
    __syncthreads();
    s[t] += x;
  }
  __syncthreads();
  if (i < N) cursor[i] = s[t] - v;          // local exclusive
  if (t == 255) bsum[blockIdx.x] = s[255];
}

__global__ __launch_bounds__(512) void k_scan_bsum(int* __restrict__ bsum, int nb)
{
  __shared__ int s[512];
  const int t = threadIdx.x;
  int v = (t < nb) ? bsum[t] : 0;
  s[t] = v;
  for (int off = 1; off < 512; off <<= 1) {
    __syncthreads();
    int x = (t >= off) ? s[t - off] : 0;
    __syncthreads();
    s[t] += x;
  }
  __syncthreads();
  if (t < nb) bsum[t] = s[t] - v;           // exclusive
}

// fused: cursor += block offset (final rowPtr) AND expand dstS runs.
__global__ __launch_bounds__(256) void k_expand_add(
    int* __restrict__ cursor, const int* __restrict__ bsum,
    const int* __restrict__ cntI, int* __restrict__ dstS, int N)
{
  int n = blockIdx.x * 256 + threadIdx.x;
  if (n >= N) return;
  int cur = cursor[n] + bsum[blockIdx.x];
  cursor[n] = cur;
  int c = cntI[n];
  for (int i = 0; i < c; i++) dstS[cur + i] = n;
}

__global__ __launch_bounds__(256) void k_scatter(
    const int* __restrict__ ei, const float* __restrict__ dts,
    int* __restrict__ cursor, int2* __restrict__ srcdtS, int E)
{
  int e = blockIdx.x * 256 + threadIdx.x;
  if (e >= E) return;
  int d = ei[E + e];
  int pos = atomicAdd(&cursor[d], 1);
  srcdtS[pos] = make_int2(ei[e], __float_as_int(dts[e]));
}

// ---------------------------------------------------------------------------
// prep_all: xb = bf16(x) padded to 24 cols; phase-1 weights W1t1/W2t1; and
// phase-2 weights W1t/W2t (folded-in former prep_w).
// ---------------------------------------------------------------------------
__global__ __launch_bounds__(256) void prep_all(
    const float* __restrict__ x, const float* __restrict__ tW1,
    const float* __restrict__ tW2, const float* __restrict__ sW1,
    const float* __restrict__ sW2, unsigned short* __restrict__ xb,
    unsigned short* __restrict__ W1t1, unsigned short* __restrict__ W2t1,
    unsigned short* __restrict__ W1t, unsigned short* __restrict__ W2t, int N)
{
  int i = blockIdx.x * 256 + threadIdx.x;
  int totalX = N * 24;
  for (int idx = i; idx < totalX; idx += gridDim.x * 256) {
    int n = idx / 24, c = idx - n * 24;
    xb[idx] = (c < 17) ? f2bf(x[n * 17 + c]) : (unsigned short)0;
  }
  if (i < 48 * 96) {
    int n = i / 96, k = i - n * 96;
    int src = (k < 17) ? k : (k >= 24 && k < 41) ? (k - 24 + 17)
            : (k >= 48 && k < 80) ? (k - 48 + 34) : -1;
    W1t1[i] = (n < 33 && src >= 0) ? f2bf(tW1[src * 33 + n]) : (unsigned short)0;
  }
  if (i < 32 * 64) {
    int n = i / 64, k = i - n * 64;
    W2t1[i] = (n < 17 && k < 33) ? f2bf(tW2[k * 17 + n]) : (unsigned short)0;
  }
  if (i < 2 * 64 * 128) {
    int l = i >> 13; int r = i & 8191; int n = r >> 7; int k = r & 127;
    W1t[i] = f2bf(sW1[((size_t)l * 128 + k) * 64 + n]);
  }
  if (i < 2 * 64 * 64) {
    int l = i >> 12; int r = i & 4095; int n = r >> 6; int k = r & 63;
    W2t[i] = f2bf(sW2[((size_t)l * 64 + k) * 64 + n]);
  }
}

// ---------------------------------------------------------------------------
// Phase 1 edge kernel (MFMA, barrier-free wave-private 16-edge tiles).
// ---------------------------------------------------------------------------
__global__ __launch_bounds__(256, 3) void phase1_edge_mfma(
    const unsigned short* __restrict__ xb, const int* __restrict__ dstS,
    const int2* __restrict__ srcdtS, const float* __restrict__ freq,
    const float* __restrict__ phs,
    const unsigned short* __restrict__ W1t1, const float* __restrict__ b1,
    const unsigned short* __restrict__ W2t1, const float* __restrict__ b2,
    float* __restrict__ accum, int E, int nwt)
{
  __shared__ unsigned short sA[64][104];
  __shared__ unsigned short sHid[64][72];
  __shared__ float sRed[64][20];
  __shared__ int   sDst[64];

  const int t = threadIdx.x;
  const int wv = t >> 6, lane = t & 63, l16 = lane & 15, quad = lane >> 4;
  const int r0 = wv * 16;

  s16x8 w1f[3][3], w2f[2][2];
  float bias1[3], bias2[2];
#pragma unroll
  for (int cb = 0; cb < 3; cb++) {
    int n = cb * 16 + l16;
#pragma unroll
    for (int kb = 0; kb < 3; kb++)
      w1f[cb][kb] = *(const s16x8*)&W1t1[n * 96 + kb * 32 + quad * 8];
    bias1[cb] = (n < 33) ? b1[n] : 0.0f;
  }
#pragma unroll
  for (int cb = 0; cb < 2; cb++) {
    int n = cb * 16 + l16;
#pragma unroll
    for (int kb = 0; kb < 2; kb++)
      w2f[cb][kb] = *(const s16x8*)&W2t1[n * 64 + kb * 32 + quad * 8];
    bias2[cb] = (n < 17) ? b2[n] : 0.0f;
  }

  // zero own-wave pad columns once
  for (int i = lane; i < 16 * 28; i += 64) {
    int rr = r0 + i / 28, c = i % 28;
    int col = (c < 6) ? 18 + c : (c < 12) ? 42 + (c - 6) : 80 + (c - 12);
    sA[rr][col] = 0;
  }
  for (int i = lane; i < 256; i += 64)
    sHid[r0 + (i >> 4)][48 + (i & 15)] = 0;

  const int gw = blockIdx.x * 4 + wv;
  const int nw = gridDim.x * 4;

  for (int tile = gw; tile < nwt; tile += nw) {
    const int eb = tile << 4;

    // staging: 4 lanes/edge (q0 xi, q1 xj, q2/q3 rel halves) — own rows only
    {
      int e_loc = lane >> 2, q = lane & 3;
      int rr = r0 + e_loc;
      int er = eb + e_loc; if (er >= E) er = E - 1;
      if (q < 2) {
        int node = q ? srcdtS[er].x : dstS[er];
        if (!q) sDst[rr] = node;
        const unsigned short* src = &xb[(size_t)node * 24];
        int base = q ? 24 : 0;
        *(uint4*)&sA[rr][base]     = *(const uint4*)&src[0];
        *(uint4*)&sA[rr][base + 8] = *(const uint4*)&src[8];
        *(unsigned int*)&sA[rr][base + 16] = *(const unsigned int*)&src[16];
      } else {
        float dt = __int_as_float(srcdtS[er].y);
        int k0 = (q == 2) ? 0 : 16;
        unsigned short tmp[16] __attribute__((aligned(16)));
#pragma unroll
        for (int j = 0; j < 16; j++)
          tmp[j] = f2bf(__cosf(fmaf(dt, freq[k0 + j], phs[k0 + j])));
        *(uint4*)&sA[rr][48 + k0]     = *(const uint4*)&tmp[0];
        *(uint4*)&sA[rr][48 + k0 + 8] = *(const uint4*)&tmp[8];
      }
    }

    // pass1: hid = relu(A @ W1 + b1)   (own row r0+l16)
    f32x4 a1[3];
#pragma unroll
    for (int cb = 0; cb < 3; cb++)
      a1[cb] = (f32x4){bias1[cb], bias1[cb], bias1[cb], bias1[cb]};
#pragma unroll
    for (int kb = 0; kb < 3; kb++) {
      s16x8 aF = *(const s16x8*)&sA[r0 + l16][kb * 32 + quad * 8];
#pragma unroll
      for (int cb = 0; cb < 3; cb++)
        a1[cb] = __builtin_amdgcn_mfma_f32_16x16x32_bf16(aF, w1f[cb][kb], a1[cb], 0, 0, 0);
    }
#pragma unroll
    for (int cb = 0; cb < 3; cb++)
#pragma unroll
      for (int reg = 0; reg < 4; reg++)
        sHid[r0 + quad * 4 + reg][cb * 16 + l16] = f2bf(fmaxf(a1[cb][reg], 0.0f));

    // pass2: u = hid @ W2 + b2
    f32x4 a2[2];
#pragma unroll
    for (int cb = 0; cb < 2; cb++)
      a2[cb] = (f32x4){bias2[cb], bias2[cb], bias2[cb], bias2[cb]};
#pragma unroll
    for (int kb = 0; kb < 2; kb++) {
      s16x8 aF = *(const s16x8*)&sHid[r0 + l16][kb * 32 + quad * 8];
#pragma unroll
      for (int cb = 0; cb < 2; cb++)
        a2[cb] = __builtin_amdgcn_mfma_f32_16x16x32_bf16(aF, w2f[cb][kb], a2[cb], 0, 0, 0);
    }

    // f -> sRed (own rows)
#pragma unroll
    for (int reg = 0; reg < 4; reg++) {
      int row = r0 + quad * 4 + reg;
      bool ok = (eb + quad * 4 + reg < E);
      sRed[row][l16] = ok ? tanh_factor(a2[0][reg]) : 0.0f;
      if (l16 == 0) sRed[row][16] = ok ? tanh_factor(a2[1][reg]) : 0.0f;
    }

    // wave-local segmented walk: lanes 0..16, col = lane, own 16 rows
    if (lane < 17) {
      int col = lane;
      float run = 0.0f;
      int cur = sDst[r0];
#pragma unroll
      for (int k = 0; k < 16; k++) {
        int d = sDst[r0 + k];
        float v = sRed[r0 + k][col];
        if (d != cur) {
          atomic_add_f32(&accum[(size_t)cur * 17 + col], run);
          run = 0.0f; cur = d;
        }
        run += v;
      }
      atomic_add_f32(&accum[(size_t)cur * 17 + col], run);
    }
  }
}

// ---------------------------------------------------------------------------
// Phase 1 node kernel: h[n] = (x[n] * (1 + acc/max(cnt,1))) @ projW + projb.
// ---------------------------------------------------------------------------
__global__ __launch_bounds__(256) void phase1_node(
    const float* __restrict__ x, const float* __restrict__ acc1,
    const int* __restrict__ cntI, const float* __restrict__ Wp,
    const float* __restrict__ bp, float* __restrict__ h, int N)
{
  __shared__ float s0[4][20];
  const int t = threadIdx.x;
  const int nb = blockIdx.x << 2;
  if (t < 68) {
    int nl = t / 17, c = t % 17;
    int n = nb + nl;
    float v = 0.0f;
    if (n < N) {
      float cnt = fmaxf((float)cntI[n], 1.0f);
      v = x[n * 17 + c] * (1.0f + acc1[n * 17 + c] / cnt);
    }
    s0[nl][c] = v;
  }
  __syncthreads();
  int nl = t >> 6, j = t & 63;
  int n = nb + nl;
  if (n < N) {
    float acc = bp[j];
#pragma unroll
    for (int c = 0; c < 17; c++) acc = fmaf(s0[nl][c], Wp[c * 64 + j], acc);
    h[n * 64 + j] = acc;
  }
}

// ---------------------------------------------------------------------------
// prep_P: P1[n] = h[n]@W1a + b1, P2[n] = h[n]@W1b (dense per-node, MFMA).
// ---------------------------------------------------------------------------
__global__ void prep_P(
    const float* __restrict__ h, const unsigned short* __restrict__ W1t,
    const float* __restrict__ b1, unsigned short* __restrict__ P1,
    unsigned short* __restrict__ P2, int N)
{
  __shared__ unsigned short sH[64][72];
  const int t = threadIdx.x;
  const int wv = t >> 6, lane = t & 63, l16 = lane & 15, quad = lane >> 4;
  const int nb = blockIdx.x << 6;

#pragma unroll
  for (int i = 0; i < 4; i++) {
    int g = t + i * 256;
    int r = g >> 4, c4 = (g & 15) << 2;
    int n = nb + r; if (n >= N) n = N - 1;
    float4 v = *(const float4*)&h[(size_t)n * 64 + c4];
    ushort4 o = { f2bf(v.x), f2bf(v.y), f2bf(v.z), f2bf(v.w) };
    *(ushort4*)&sH[r][c4] = o;
  }
  __syncthreads();

  const int n = nb + wv * 16 + l16;
#pragma unroll
  for (int half = 0; half < 2; half++) {
    f32x4 acc[4];
#pragma unroll
    for (int cb = 0; cb < 4; cb++) {
      if (half == 0) {
        float4 bv = *(const float4*)&b1[cb * 16 + quad * 4];
        acc[cb] = (f32x4){bv.x, bv.y, bv.z, bv.w};
      } else {
        acc[cb] = (f32x4){0.0f, 0.0f, 0.0f, 0.0f};
      }
    }
#pragma unroll
    for (int kb = 0; kb < 2; kb++) {
      s16x8 bF = *(const s16x8*)&sH[wv * 16 + l16][kb * 32 + quad * 8];
#pragma unroll
      for (int cb = 0; cb < 4; cb++) {
        s16x8 aF = *(const s16x8*)&W1t[(cb * 16 + l16) * 128 + half * 64 + kb * 32 + quad * 8];
        acc[cb] = __builtin_amdgcn_mfma_f32_16x16x32_bf16(aF, bF, acc[cb], 0, 0, 0);
      }
    }
    if (n < N) {
      unsigned short* P = half ? P2 : P1;
#pragma unroll
      for (int cb = 0; cb < 4; cb++) {
        ushort4 o = { f2bf(acc[cb][0]), f2bf(acc[cb][1]),
                      f2bf(acc[cb][2]), f2bf(acc[cb][3]) };
        *(ushort4*)&P[(size_t)n * 64 + cb * 16 + quad * 4] = o;
      }
    }
  }
}

// ---------------------------------------------------------------------------
// Phase 2 edge kernel — barrier-free wave-private 16-edge tiles.
// hidden = relu(P1[dst]+P2[src]) built in registers; u^T = W2t @ hidden^T.
// ---------------------------------------------------------------------------
__global__ __launch_bounds__(256, 4) void phase2_edge(
    const unsigned short* __restrict__ P1, const unsigned short* __restrict__ P2,
    const int* __restrict__ dstS, const int2* __restrict__ srcdtS,
    const unsigned short* __restrict__ W2t, const float* __restrict__ b2,
    float* __restrict__ accum, int E, int nwt)
{
  __shared__ unsigned short sA[64][136];   // [edge][0:64]=P1[dst], [64:128]=P2[src]
  __shared__ int sDst[64];
  float* sRedF = (float*)&sA[0][0];        // aliased 64x68 f32 (same stride 272B)

  const int t = threadIdx.x;
  const int wv = t >> 6, lane = t & 63, l16 = lane & 15, quad = lane >> 4;
  const int r0 = wv * 16;

  s16x8 w2f[4][2];
  f32x4 bias2v[4];
#pragma unroll
  for (int cb = 0; cb < 4; cb++) {
#pragma unroll
    for (int kb = 0; kb < 2; kb++)
      w2f[cb][kb] = *(const s16x8*)&W2t[(cb * 16 + l16) * 64 + kb * 32 + quad * 8];
    float4 bv = *(const float4*)&b2[cb * 16 + quad * 4];
    bias2v[cb] = (f32x4){bv.x, bv.y, bv.z, bv.w};
  }

  const int gw = blockIdx.x * 4 + wv;
  const int nw = gridDim.x * 4;
  const int eRow = r0 + l16;

  for (int tile = gw; tile < nwt; tile += nw) {
    const int eb = tile << 4;

    // staging: 4 lanes/edge, 64B contiguous per lane, own rows only
    {
      int e_loc = lane >> 2, q = lane & 3;
      int rr = r0 + e_loc;
      int er = eb + e_loc; if (er >= E) er = E - 1;
      int node;
      if (q < 2) { node = dstS[er]; if (!q) sDst[rr] = node; }
      else       node = srcdtS[er].x;
      const unsigned short* src = (q < 2 ? P1 : P2) + (size_t)node * 64 + (q & 1) * 32;
      int cb0 = q * 32;
#pragma unroll
      for (int j = 0; j < 4; j++)
        *(uint4*)&sA[rr][cb0 + j * 8] = *(const uint4*)&src[j * 8];
    }

    // hidden B-frags: relu(P1+P2), packed bf16 (own row)
    s16x8 hidf[2];
#pragma unroll
    for (int kb = 0; kb < 2; kb++) {
      s16x8 x1 = *(const s16x8*)&sA[eRow][kb * 32 + quad * 8];
      s16x8 x2 = *(const s16x8*)&sA[eRow][64 + kb * 32 + quad * 8];
      s16x8 hf;
#pragma unroll
      for (int j = 0; j < 8; j++) {
        float a = bf2f((unsigned short)x1[j]);
        float b = bf2f((unsigned short)x2[j]);
        hf[j] = (short)f2bf(fmaxf(a + b, 0.0f));
      }
      hidf[kb] = hf;
    }

    // u^T[n2][edge] = W2t @ hidden^T + b2
    f32x4 acc[4];
#pragma unroll
    for (int cb = 0; cb < 4; cb++) acc[cb] = bias2v[cb];
#pragma unroll
    for (int kb = 0; kb < 2; kb++)
#pragma unroll
      for (int cb = 0; cb < 4; cb++)
        acc[cb] = __builtin_amdgcn_mfma_f32_16x16x32_bf16(w2f[cb][kb], hidf[kb], acc[cb], 0, 0, 0);

    // f = 2*tanh(u)-1 -> sRedF (own rows; same-wave ordering)
    bool ok = (eb + l16 < E);
#pragma unroll
    for (int cb = 0; cb < 4; cb++) {
      f32x4 f;
#pragma unroll
      for (int reg = 0; reg < 4; reg++)
        f[reg] = ok ? tanh_factor(acc[cb][reg]) : 0.0f;
      *(f32x4*)&sRedF[eRow * 68 + cb * 16 + quad * 4] = f;
    }

    // wave-local segmented walk: lane = col, own 16 rows
    {
      float run = 0.0f;
      int cur = sDst[r0];
#pragma unroll
      for (int k = 0; k < 16; k++) {
        int d = sDst[r0 + k];                 // wave-uniform
        float v = sRedF[(r0 + k) * 68 + lane];
        if (d != cur) {                       // wave-uniform branch
          atomic_add_f32(&accum[(size_t)cur * 64 + lane], run);
          run = 0.0f; cur = d;
        }
        run += v;
      }
      atomic_add_f32(&accum[(size_t)cur * 64 + lane], run);
    }
  }
}

// ---------------------------------------------------------------------------
// Node update + BN statistics: h = h * (1 + acc/cnt); re-zeroes accum for the
// next layer (replaces a 25.6MB memset dispatch).
// ---------------------------------------------------------------------------
__global__ __launch_bounds__(256) void node_update_bn(
    float* __restrict__ h, float* __restrict__ accum,
    const int* __restrict__ cntI, float* __restrict__ bns,
    float* __restrict__ bnq, int N)
{
  const int t = threadIdx.x;
  float ls = 0.0f, lq = 0.0f;
  int total = N * 64;
  for (int idx = blockIdx.x * 256 + t; idx < total; idx += gridDim.x * 256) {
    int n = idx >> 6;
    float cnt = fmaxf((float)cntI[n], 1.0f);
    float v = h[idx] * (1.0f + accum[idx] / cnt);
    accum[idx] = 0.0f;                 // ready for next layer's scatter
    h[idx] = v;
    ls += v; lq += v * v;
  }
  __shared__ float ss[256], sq[256];
  ss[t] = ls; sq[t] = lq;
  __syncthreads();
  if (t < 64) {
    float s = ss[t] + ss[t + 64] + ss[t + 128] + ss[t + 192];
    float q = sq[t] + sq[t + 64] + sq[t + 128] + sq[t + 192];
    atomic_add_f32(&bns[t], s);
    atomic_add_f32(&bnq[t], q);
  }
}

// ---------------------------------------------------------------------------
// BN apply + relu (in place).
// ---------------------------------------------------------------------------
__global__ __launch_bounds__(256) void bn_apply_relu(
    float* __restrict__ d, const float* __restrict__ bns,
    const float* __restrict__ bnq, const float* __restrict__ gam,
    const float* __restrict__ bet, int total, int cmask, float invRows)
{
  for (int idx = blockIdx.x * 256 + threadIdx.x; idx < total;
       idx += gridDim.x * 256) {
    int c = idx & cmask;
    float m = bns[c] * invRows;
    float var = bnq[c] * invRows - m * m;
    float sc = gam[c] * rsqrtf(var + 1e-5f);
    d[idx] = fmaxf((d[idx] - m) * sc + bet[c], 0.0f);
  }
}

// ---------------------------------------------------------------------------
// Classifier matmul (rows x K @ K x C) + bias, with BN stats.
// ---------------------------------------------------------------------------
__global__ __launch_bounds__(256) void clf_mm_bn(
    const float* __restrict__ in, const float* __restrict__ W,
    const float* __restrict__ b, float* __restrict__ out,
    float* __restrict__ bns, float* __restrict__ bnq,
    int rows, int K, int cshift)
{
  const int t = threadIdx.x;
  const int C = 1 << cshift;
  int total = rows << cshift;
  float ls = 0.0f, lq = 0.0f;
  for (int idx = blockIdx.x * 256 + t; idx < total; idx += gridDim.x * 256) {
    int n = idx >> cshift;
    int c = idx & (C - 1);
    float acc = b[c];
#pragma unroll 8
    for (int k = 0; k < K; k++) acc = fmaf(in[n * K + k], W[(k << cshift) + c], acc);
    out[idx] = acc;
    ls += acc; lq += acc * acc;
  }
  __shared__ float ss[256], sq[256];
  ss[t] = ls; sq[t] = lq;
  __syncthreads();
  if (t < C) {
    float s = 0.0f, q = 0.0f;
    for (int i = t; i < 256; i += C) { s += ss[i]; q += sq[i]; }
    atomic_add_f32(&bns[t], s);
    atomic_add_f32(&bnq[t], q);
  }
}

__global__ __launch_bounds__(256) void clf_final(
    const float* __restrict__ z2, const float* __restrict__ W3,
    const float* __restrict__ b3, float* __restrict__ out, int rows)
{
  int n = blockIdx.x * 256 + threadIdx.x;
  if (n >= rows) return;
  float acc = b3[0];
#pragma unroll
  for (int k = 0; k < 32; k++) acc = fmaf(z2[n * 32 + k], W3[k], acc);
  out[n] = acc;
}

// ---------------------------------------------------------------------------
extern "C" void kernel_launch(void* const* d_in, const int* in_sizes, int n_in,
                              void* d_out, int out_size, void* d_ws, size_t ws_size,
                              hipStream_t stream)
{
  const float* x    = (const float*)d_in[0];
  const int*   ei   = (const int*)  d_in[1];
  const float* dts  = (const float*)d_in[2];
  const float* freq = (const float*)d_in[4];
  const float* phs  = (const float*)d_in[5];
  const float* tW1  = (const float*)d_in[6];
  const float* tb1  = (const float*)d_in[7];
  const float* tW2  = (const float*)d_in[8];
  const float* tb2  = (const float*)d_in[9];
  const float* pW   = (const float*)d_in[10];
  const float* pb   = (const float*)d_in[11];
  const float* sW1  = (const float*)d_in[12];
  const float* sb1  = (const float*)d_in[13];
  const float* sW2  = (const float*)d_in[14];
  const float* sb2  = (const float*)d_in[15];
  const float* bng  = (const float*)d_in[16];
  const float* bnb  = (const float*)d_in[17];
  const float* cW1  = (const float*)d_in[18];
  const float* cb1  = (const float*)d_in[19];
  const float* cg1  = (const float*)d_in[20];
  const float* cbb1 = (const float*)d_in[21];
  const float* cW2  = (const float*)d_in[22];
  const float* cb2  = (const float*)d_in[23];
  const float* cg2  = (const float*)d_in[24];
  const float* cbb2 = (const float*)d_in[25];
  const float* cW3  = (const float*)d_in[26];
  const float* cb3  = (const float*)d_in[27];
  float* out = (float*)d_out;

  const int N = in_sizes[0] / 17;
  const int E = in_sizes[1] / 2;
  const int B = out_size;

  // ---- workspace layout (byte offsets, union region for phase-local data) --
  char* base = (char*)d_ws;
  size_t off = 0;
  float* h    = (float*)(base + off); off += (size_t)N * 64 * 4;
  float* acc2 = (float*)(base + off); off += (size_t)N * 64 * 4;
  char*  uni  = base + off;           off += (size_t)N * 64 * 4;  // union
  float* bnsAll = (float*)(base + off); off += 8 * 64 * 4;        // 8 slots
  unsigned short* W1t = (unsigned short*)(base + off); off += 2 * 64 * 128 * 2;
  unsigned short* W2t = (unsigned short*)(base + off); off += 2 * 64 * 64 * 2;
  int* cntI   = (int*)(base + off); off += (size_t)N * 4;
  int* cursor = (int*)(base + off); off += (size_t)N * 4;
  int* bsum   = (int*)(base + off); off += 512 * 4;
  int* dstS   = (int*)(base + off); off += (size_t)E * 4;
  off = (off + 15) & ~(size_t)15;
  int2* srcdtS = (int2*)(base + off); off += (size_t)E * 8;
  size_t needed = off;
  if (ws_size < needed) return;  // fail visibly (output stays poisoned)

  // union members (phase1 | phase2 | classifier — lifetimes disjoint)
  float* acc1 = (float*)uni;                                     // N*17 f32
  unsigned short* xb   = (unsigned short*)(uni + (size_t)N * 17 * 4); // N*24
  unsigned short* W1t1 = xb + (size_t)N * 24;                    // 48*96
  unsigned short* W2t1 = W1t1 + 48 * 96;                         // 32*64
  unsigned short* P1 = (unsigned short*)uni;                     // N*64
  unsigned short* P2 = P1 + (size_t)N * 64;                      // N*64
  float* z1 = (float*)uni;                                       // B*64
  float* z2 = z1 + (size_t)B * 64;                               // B*32

  const int nwt = (E + 15) / 16;
  const int NB = (N + 255) / 256;
  if (NB > 512) return;

  // ---- init (poisoned ws): counts, acc1, acc2(layer0), BN-stat slots ----
  hipMemsetAsync(cntI, 0, (size_t)N * 4, stream);
  hipMemsetAsync(acc1, 0, (size_t)N * 17 * 4, stream);
  hipMemsetAsync(acc2, 0, (size_t)N * 64 * 4, stream);
  hipMemsetAsync(bnsAll, 0, 8 * 64 * 4, stream);

  // ---- counting sort by dst (yields counts + dstS) + weight/x prep ----
  k_hist<<<(E + 255) / 256, 256, 0, stream>>>(ei, cntI, E);
  k_scan_block<<<NB, 256, 0, stream>>>(cntI, cursor, bsum, N);
  k_scan_bsum<<<1, 512, 0, stream>>>(bsum, NB);
  k_expand_add<<<NB, 256, 0, stream>>>(cursor, bsum, cntI, dstS, N);
  k_scatter<<<(E + 255) / 256, 256, 0, stream>>>(ei, dts, cursor, srcdtS, E);
  prep_all<<<(N * 24 + 255) / 256, 256, 0, stream>>>(
      x, tW1, tW2, sW1, sW2, xb, W1t1, W2t1, W1t, W2t, N);

  // ---- phase 1 ----
  phase1_edge_mfma<<<768, 256, 0, stream>>>(
      xb, dstS, srcdtS, freq, phs, W1t1, tb1, W2t1, tb2, acc1, E, nwt);
  phase1_node<<<(N + 3) / 4, 256, 0, stream>>>(x, acc1, cntI, pW, pb, h, N);

  // ---- phase 2: L = 2 message-passing + BN layers ----
  for (int l = 0; l < 2; l++) {
    float* bns = bnsAll + l * 128;
    float* bnq = bns + 64;
    prep_P<<<(N + 63) / 64, 256, 0, stream>>>(
        h, W1t + (size_t)l * 64 * 128, sb1 + l * 64, P1, P2, N);
    phase2_edge<<<1024, 256, 0, stream>>>(
        P1, P2, dstS, srcdtS, W2t + (size_t)l * 64 * 64, sb2 + l * 64,
        acc2, E, nwt);
    node_update_bn<<<1024, 256, 0, stream>>>(h, acc2, cntI, bns, bnq, N);
    bn_apply_relu<<<2048, 256, 0, stream>>>(
        h, bns, bnq, bng + l * 64, bnb + l * 64, N * 64, 63, 1.0f / (float)N);
  }

  // ---- classifier on first B rows of h ----
  {
    float* bns = bnsAll + 256;   // slot 2 pair
    float* bnq = bns + 64;
    clf_mm_bn<<<2500, 256, 0, stream>>>(h, cW1, cb1, z1, bns, bnq, B, 64, 6);
    bn_apply_relu<<<1024, 256, 0, stream>>>(z1, bns, bnq, cg1, cbb1,
                                            B * 64, 63, 1.0f / (float)B);
  }
  {
    float* bns = bnsAll + 384;   // slot 3 pair
    float* bnq = bns + 64;
    clf_mm_bn<<<1250, 256, 0, stream>>>(z1, cW2, cb2, z2, bns, bnq, B, 64, 5);
    bn_apply_relu<<<512, 256, 0, stream>>>(z2, bns, bnq, cg2, cbb2,
                                           B * 32, 31, 1.0f / (float)B);
  }
  clf_final<<<(B + 255) / 256, 256, 0, stream>>>(z2, cW3, cb3, out, B);
}